// Round 2
// baseline (2974.161 us; speedup 1.0000x reference)
//
#include <hip/hip_runtime.h>
#include <hip/hip_bf16.h>

// T=4, B=16, C=768, H=W=16 -> N=256, Ch=3072, heads=12, d=64
#define T_ 4
#define B_ 16
#define C_ 768
#define N_ 256
#define CH_ 3072

// ---------------------------------------------------------------------------
// Batched fp32 GEMM: O[bt,m,n] = sum_{k<Kc} W[m, k] * X[bt,k,n]
//   W row stride = ldW (W may be a sub-block of a larger matrix)
//   X layout [batch][Kc][256] contiguous, O layout [batch][M][256] contiguous
//   accumulate=0: O = acc + bias;  accumulate=1: O += acc (bias ignored)
// Block tile 128x128, 256 threads, 8x8 microtile. n-microtile split in two
// 4-wide halves (tx*4, tx*4+64) so LDS b128 reads are <=2-way bank aliased.
// ---------------------------------------------------------------------------
__global__ __launch_bounds__(256, 4) void gemm_batched(
    const float* __restrict__ W, int ldW,
    const float* __restrict__ X, int Kc,
    float* __restrict__ O, int M,
    const float* __restrict__ bias, int accumulate)
{
    const int N = N_;
    const int bt = blockIdx.z;
    const int m0 = blockIdx.y * 128;
    const int n0 = blockIdx.x * 128;
    const float* __restrict__ Xb = X + (size_t)bt * Kc * N;
    float* __restrict__ Ob = O + (size_t)bt * M * N;

    __shared__ float As[16][132];   // [k][m]
    __shared__ float Bs[16][132];   // [k][n]

    const int tid = threadIdx.x;
    const int tx = tid & 15;
    const int ty = tid >> 4;

    // A staging: 128 rows x 16 k = 512 float4, 2 per thread
    const int ar = tid >> 2;          // 0..63 (+64 second)
    const int ak = (tid & 3) << 2;    // 0,4,8,12
    // B staging: 16 rows x 128 n = 512 float4, 2 per thread
    const int br = tid >> 4;          // 0..15
    const int bc = (tid & 15) << 2;   // 0..60 (+64 second)

    float acc[8][8];
    #pragma unroll
    for (int i = 0; i < 8; ++i)
        #pragma unroll
        for (int j = 0; j < 8; ++j) acc[i][j] = 0.0f;

    for (int k0 = 0; k0 < Kc; k0 += 16) {
        const float4 a0 = *(const float4*)(W + (size_t)(m0 + ar) * ldW + (k0 + ak));
        const float4 a1 = *(const float4*)(W + (size_t)(m0 + ar + 64) * ldW + (k0 + ak));
        const float4 b0 = *(const float4*)(Xb + (size_t)(k0 + br) * N + (n0 + bc));
        const float4 b1 = *(const float4*)(Xb + (size_t)(k0 + br) * N + (n0 + bc + 64));
        __syncthreads();   // protect previous iteration's LDS reads
        As[ak + 0][ar] = a0.x; As[ak + 1][ar] = a0.y;
        As[ak + 2][ar] = a0.z; As[ak + 3][ar] = a0.w;
        As[ak + 0][ar + 64] = a1.x; As[ak + 1][ar + 64] = a1.y;
        As[ak + 2][ar + 64] = a1.z; As[ak + 3][ar + 64] = a1.w;
        *(float4*)&Bs[br][bc] = b0;
        *(float4*)&Bs[br][bc + 64] = b1;
        __syncthreads();
        #pragma unroll
        for (int kk = 0; kk < 16; ++kk) {
            const float4 av0 = *(const float4*)&As[kk][ty * 8];
            const float4 av1 = *(const float4*)&As[kk][ty * 8 + 4];
            const float4 bv0 = *(const float4*)&Bs[kk][tx * 4];
            const float4 bv1 = *(const float4*)&Bs[kk][tx * 4 + 64];
            const float a[8] = {av0.x, av0.y, av0.z, av0.w, av1.x, av1.y, av1.z, av1.w};
            const float b[8] = {bv0.x, bv0.y, bv0.z, bv0.w, bv1.x, bv1.y, bv1.z, bv1.w};
            #pragma unroll
            for (int i = 0; i < 8; ++i)
                #pragma unroll
                for (int j = 0; j < 8; ++j)
                    acc[i][j] += a[i] * b[j];
        }
    }

    #pragma unroll
    for (int i = 0; i < 8; ++i) {
        const int m = m0 + ty * 8 + i;
        float* op0 = Ob + (size_t)m * N + n0 + tx * 4;
        float* op1 = op0 + 64;
        float4 o0, o1;
        if (accumulate) {
            const float4 e0 = *(const float4*)op0;
            const float4 e1 = *(const float4*)op1;
            o0.x = e0.x + acc[i][0]; o0.y = e0.y + acc[i][1];
            o0.z = e0.z + acc[i][2]; o0.w = e0.w + acc[i][3];
            o1.x = e1.x + acc[i][4]; o1.y = e1.y + acc[i][5];
            o1.z = e1.z + acc[i][6]; o1.w = e1.w + acc[i][7];
        } else {
            const float bb = bias ? bias[m] : 0.0f;
            o0.x = acc[i][0] + bb; o0.y = acc[i][1] + bb;
            o0.z = acc[i][2] + bb; o0.w = acc[i][3] + bb;
            o1.x = acc[i][4] + bb; o1.y = acc[i][5] + bb;
            o1.z = acc[i][6] + bb; o1.w = acc[i][7] + bb;
        }
        *(float4*)op0 = o0;
        *(float4*)op1 = o1;
    }
}

// ---------------------------------------------------------------------------
// BN (inference) + LIF over T. buf layout [T,B,Cc,256].
// BN params: g=bnp[c], beta=bnp[Cs+c], mean=bnp[2Cs+c], var=bnp[3Cs+c]
// (Cs = row stride of the [4,Ch] param pack; bnp may be offset for chunks).
// out[t] = spike (+ addin[t] if addin != null). In-place (pre==out) is safe.
// ---------------------------------------------------------------------------
__global__ void bnlif_kernel(const float* pre,
                             const float* __restrict__ addin,
                             float* out,
                             const float* __restrict__ bnp, int Cc, int Cs)
{
    const int n = threadIdx.x;       // 0..255
    const int c = blockIdx.x;        // 0..Cc-1
    const int b = blockIdx.y;        // 0..15
    const float g  = bnp[c];
    const float be = bnp[Cs + c];
    const float mu = bnp[2 * Cs + c];
    const float va = bnp[3 * Cs + c];
    const float scale = g / sqrtf(va + 1e-5f);
    const size_t base = ((size_t)b * Cc + c) * N_ + n;
    const size_t tstride = (size_t)B_ * Cc * N_;
    float v = 0.0f;
    #pragma unroll
    for (int t = 0; t < T_; ++t) {
        const size_t idx = base + (size_t)t * tstride;
        const float u = (pre[idx] - mu) * scale + be;
        v = v + (u - v) * 0.5f;                 // TAU = 2
        const float s = (v >= 1.0f) ? 1.0f : 0.0f;
        float o = s;
        if (addin) o += addin[idx];
        out[idx] = o;
        v = (s > 0.0f) ? 0.0f : v;              // hard reset
    }
}

// ---------------------------------------------------------------------------
// attn[t,b,h,n] = LIF_t( sum_d q_spike[t,b,h*64+d,n] )
// ---------------------------------------------------------------------------
__global__ void attn_kernel(const float* __restrict__ q, float* __restrict__ attn)
{
    const int n = threadIdx.x;      // 0..255
    const int h = blockIdx.x;       // 0..11
    const int b = blockIdx.y;       // 0..15
    float v = 0.0f;
    #pragma unroll
    for (int t = 0; t < T_; ++t) {
        const float* qp = q + (((size_t)(t * B_ + b) * C_) + h * 64) * N_ + n;
        float s = 0.0f;
        #pragma unroll 8
        for (int d = 0; d < 64; ++d) s += qp[(size_t)d * N_];
        v = v + (s - v) * 0.5f;
        const float sp = (v >= 1.0f) ? 1.0f : 0.0f;
        attn[((size_t)(t * B_ + b) * 12 + h) * N_ + n] = sp;
        v = (sp > 0.0f) ? 0.0f : v;
    }
}

// ---------------------------------------------------------------------------
// a[t,b,c,n] = k_spike[t,b,c,n] * attn[t,b,c>>6,n]   (in-place on k buffer)
// ---------------------------------------------------------------------------
__global__ void mula_kernel(float* k, const float* __restrict__ attn)
{
    const int n = threadIdx.x;      // 0..255
    const int c = blockIdx.x;       // 0..767
    const int tb = blockIdx.y;      // 0..63
    const size_t ki = ((size_t)tb * C_ + c) * N_ + n;
    const size_t ai = ((size_t)tb * 12 + (c >> 6)) * N_ + n;
    k[ki] *= attn[ai];
}

extern "C" void kernel_launch(void* const* d_in, const int* in_sizes, int n_in,
                              void* d_out, int out_size, void* d_ws, size_t ws_size,
                              hipStream_t stream) {
    const float* x    = (const float*)d_in[0];
    const float* w_q  = (const float*)d_in[1];
    const float* bn_q = (const float*)d_in[2];
    const float* w_k  = (const float*)d_in[3];
    const float* bn_k = (const float*)d_in[4];
    const float* w_p  = (const float*)d_in[5];
    const float* b_p  = (const float*)d_in[6];
    const float* bn_p = (const float*)d_in[7];
    const float* w1   = (const float*)d_in[8];
    const float* b1   = (const float*)d_in[9];
    const float* bn1  = (const float*)d_in[10];
    const float* w2   = (const float*)d_in[11];
    const float* b2   = (const float*)d_in[12];
    const float* bn2  = (const float*)d_in[13];

    const size_t SZ1 = (size_t)T_ * B_ * C_ * N_;    // 12,582,912 floats (50.3 MB)
    const size_t SZA = (size_t)T_ * B_ * 12 * N_;    // 196,608 floats

    // Workspace layout (~76.3 MB total):
    float* qbuf  = (float*)d_ws;          // q_pre -> q_spk -> p_pre -> y
    float* attnb = qbuf + SZ1;            // attn spikes
    float* z1mc  = attnb + SZA;           // MLP z1 chunk [T*B, 384, 256] (25.2 MB)
    // d_out doubles as scratch with disjoint lifetimes:
    //   k_pre -> k_spk -> a (consumed by p-GEMM) -> z2 accumulator -> final out
    float* dob = (float*)d_out;

    const dim3 blk(256);

    // q_pre = w_q @ x ; k_pre = w_k @ x
    gemm_batched<<<dim3(2, 6, 64), blk, 0, stream>>>(w_q, C_, x, C_, qbuf, C_, nullptr, 0);
    gemm_batched<<<dim3(2, 6, 64), blk, 0, stream>>>(w_k, C_, x, C_, dob, C_, nullptr, 0);
    // q,k spikes (in place)
    bnlif_kernel<<<dim3(C_, B_), blk, 0, stream>>>(qbuf, nullptr, qbuf, bn_q, C_, C_);
    bnlif_kernel<<<dim3(C_, B_), blk, 0, stream>>>(dob, nullptr, dob, bn_k, C_, C_);
    // attn spikes from q
    attn_kernel<<<dim3(12, B_), blk, 0, stream>>>(qbuf, attnb);
    // a = attn * k (in place on d_out)
    mula_kernel<<<dim3(C_, T_ * B_), blk, 0, stream>>>(dob, attnb);
    // p_pre = w_p @ a + b_p  (into qbuf; q spikes no longer needed)
    gemm_batched<<<dim3(2, 6, 64), blk, 0, stream>>>(w_p, C_, dob, C_, qbuf, C_, b_p, 0);
    // y = x + spike(bn_p(p_pre))  (in place on qbuf); 'a' in d_out now dead
    bnlif_kernel<<<dim3(C_, B_), blk, 0, stream>>>(qbuf, x, qbuf, bn_p, C_, C_);

    // MLP chunked over Ch in 8 chunks of 384 output channels.
    // z2 accumulates into d_out: chunk 0 writes (with bias b2), chunks 1..7 add.
    for (int mc = 0; mc < 8; ++mc) {
        const int c0 = mc * 384;
        // z1_chunk = w1[c0:c0+384, :] @ y + b1[c0:c0+384]
        gemm_batched<<<dim3(2, 3, 64), blk, 0, stream>>>(
            w1 + (size_t)c0 * C_, C_, qbuf, C_, z1mc, 384, b1 + c0, 0);
        // s1_chunk = spike(bn1_chunk(z1_chunk)) (in place)
        bnlif_kernel<<<dim3(384, B_), blk, 0, stream>>>(z1mc, nullptr, z1mc, bn1 + c0, 384, CH_);
        // z2 += w2[:, c0:c0+384] @ s1_chunk   (+ b2 on first chunk)
        gemm_batched<<<dim3(2, 6, 64), blk, 0, stream>>>(
            w2 + c0, CH_, z1mc, 384, dob, C_, b2, mc > 0 ? 1 : 0);
    }
    // out = y + spike(bn2(z2))  (in place on d_out, addin = y)
    bnlif_kernel<<<dim3(C_, B_), blk, 0, stream>>>(dob, qbuf, dob, bn2, C_, C_);
}

// Round 3
// 1206.178 us; speedup vs baseline: 2.4658x; 2.4658x over previous
//
#include <hip/hip_runtime.h>

// T=4, B=16, C=768, H=W=16 -> N=256, Ch=3072, heads=12, d=64
#define T_ 4
#define B_ 16
#define C_ 768
#define N_ 256
#define CH_ 3072

typedef _Float16 f16x8 __attribute__((ext_vector_type(8)));
typedef float f32x4 __attribute__((ext_vector_type(4)));

// ---------------------------------------------------------------------------
// Blocked operand layout (both A=weights and B=activations):
//   per 128(row) x 32(k) tile: 512 chunks of 8 halfs (16B).
//   chunk index c = k8*128 + row   (k8 = (k_local>>3), row = row_local)
//   chunk holds k = kt*32 + k8*8 + (0..7) for its row.
// A arrays: [mb][KT][512 chunks]; B arrays: [bt][nb(2)][KT][512 chunks].
// This makes global_load_lds staging lane-linear AND ds_read_b128 frag reads
// bank-uniform (quad = row mod 8 -> 8 lanes per bank-quad = optimal).
// ---------------------------------------------------------------------------

__device__ __forceinline__ void stage_tile(const _Float16* g, _Float16* l,
                                           int wv, int ln)
{
#pragma unroll
    for (int i = 0; i < 2; ++i) {
        const int c = wv * 128 + i * 64;
        __builtin_amdgcn_global_load_lds(
            (const __attribute__((address_space(1))) void*)(g + (size_t)(c + ln) * 8),
            (__attribute__((address_space(3))) void*)(l + (size_t)c * 8),
            16, 0, 0);
    }
}

// ---------------------------------------------------------------------------
// MFMA GEMM: O[bt, m, n] = oscale * sum_k (A0+A1)[m,k] * (B0[+B1])[k,n]  (+bias)
// NB=2: general fp32 operand (terms A0B0, A0B1, A1B0)
// NB=1: exact fp16 operand B (spikes)   (terms A0B0, A1B0)
// Tile 128x128, 4 waves, each wave 64x64 = 4x4 mfma_f32_16x16x32_f16 tiles.
// ---------------------------------------------------------------------------
template <int NB>
__global__ __launch_bounds__(256) void gemm_mfma(
    const _Float16* __restrict__ A0, const _Float16* __restrict__ A1,
    const _Float16* __restrict__ B0, const _Float16* __restrict__ B1,
    float* __restrict__ O, int M,
    const float* __restrict__ bias, int accumulate, float oscale,
    int KTA, int ktA0, int mbA0, int KTB, int nkt)
{
    const int nb = blockIdx.x;            // n block (0..1)
    const int by = blockIdx.y;            // output m block
    const int bt = blockIdx.z;            // batch (t*16+b)
    const int mbA = mbA0 + by;

    __shared__ _Float16 lds[(2 + NB) * 4096];

    const int tid = threadIdx.x;
    const int wv = tid >> 6;
    const int ln = tid & 63;
    const int mw = (wv >> 1) * 64;
    const int nw = (wv & 1) * 64;

    f32x4 acc[4][4];
#pragma unroll
    for (int i = 0; i < 4; ++i)
#pragma unroll
        for (int j = 0; j < 4; ++j)
            acc[i][j] = (f32x4){0.f, 0.f, 0.f, 0.f};

    const _Float16* ga0 = A0 + ((size_t)mbA * KTA + ktA0) * 4096;
    const _Float16* ga1 = A1 + ((size_t)mbA * KTA + ktA0) * 4096;
    const _Float16* gb0 = B0 + (((size_t)bt * 2 + nb) * KTB) * 4096;
    const _Float16* gb1 = (NB == 2) ? B1 + (((size_t)bt * 2 + nb) * KTB) * 4096 : nullptr;

    const int ca = (ln >> 4) * 128 + mw + (ln & 15);   // A frag chunk base
    const int cb = (ln >> 4) * 128 + nw + (ln & 15);   // B frag chunk base

    for (int kt = 0; kt < nkt; ++kt) {
        __syncthreads();   // protect previous iteration's LDS frag reads
        stage_tile(ga0, &lds[0], wv, ln);
        stage_tile(ga1, &lds[4096], wv, ln);
        stage_tile(gb0, &lds[2 * 4096], wv, ln);
        if (NB == 2) stage_tile(gb1, &lds[3 * 4096], wv, ln);
        __syncthreads();   // compiler drains vmcnt before barrier

        f16x8 a0[4], a1[4];
#pragma unroll
        for (int mt = 0; mt < 4; ++mt) {
            a0[mt] = *(const f16x8*)&lds[(ca + mt * 16) * 8];
            a1[mt] = *(const f16x8*)&lds[4096 + (ca + mt * 16) * 8];
        }
#pragma unroll
        for (int nt = 0; nt < 4; ++nt) {
            const f16x8 b0 = *(const f16x8*)&lds[2 * 4096 + (cb + nt * 16) * 8];
            f16x8 b1;
            if (NB == 2) b1 = *(const f16x8*)&lds[3 * 4096 + (cb + nt * 16) * 8];
#pragma unroll
            for (int mt = 0; mt < 4; ++mt) {
                acc[mt][nt] = __builtin_amdgcn_mfma_f32_16x16x32_f16(a0[mt], b0, acc[mt][nt], 0, 0, 0);
                acc[mt][nt] = __builtin_amdgcn_mfma_f32_16x16x32_f16(a1[mt], b0, acc[mt][nt], 0, 0, 0);
                if (NB == 2)
                    acc[mt][nt] = __builtin_amdgcn_mfma_f32_16x16x32_f16(a0[mt], b1, acc[mt][nt], 0, 0, 0);
            }
        }
        ga0 += 4096; ga1 += 4096; gb0 += 4096;
        if (NB == 2) gb1 += 4096;
    }

    // Epilogue. C/D layout: col(n) = lane&15, row(m) = (lane>>4)*4 + reg.
    const int lm = (ln >> 4) * 4;
    const int lnn = ln & 15;
#pragma unroll
    for (int mt = 0; mt < 4; ++mt) {
#pragma unroll
        for (int r = 0; r < 4; ++r) {
            const int m = by * 128 + mw + mt * 16 + lm + r;
            const float bb = bias ? bias[m] : 0.0f;
#pragma unroll
            for (int nt = 0; nt < 4; ++nt) {
                const int n = nb * 128 + nw + nt * 16 + lnn;
                float* op = O + ((size_t)bt * M + m) * 256 + n;
                float v = acc[mt][nt][r] * oscale;
                v += accumulate ? *op : bb;
                *op = v;
            }
        }
    }
}

// ---------------------------------------------------------------------------
// Weight split: W fp32 [M][ldW] -> 2 fp16 chunk arrays, blocked A layout,
// values scaled by `scale` (2^12) so the lo chunk stays in fp16 normal range.
// grid (M/128, KT), block (128, 4): tx = row-in-block, ty = k8.
// ---------------------------------------------------------------------------
__global__ void splitW(const float* __restrict__ W, int ldW,
                       _Float16* __restrict__ C0, _Float16* __restrict__ C1,
                       int KT, float scale)
{
    const int mb = blockIdx.x, kt = blockIdx.y;
    const int mm = threadIdx.x, k8 = threadIdx.y;
    const float* src = W + (size_t)(mb * 128 + mm) * ldW + kt * 32 + k8 * 8;
    const size_t cb = (((size_t)mb * KT + kt) * 512 + k8 * 128 + mm) * 8;
    f16x8 h0, h1;
#pragma unroll
    for (int j = 0; j < 8; ++j) {
        const float x = src[j] * scale;
        const _Float16 h = (_Float16)x;
        h0[j] = h;
        h1[j] = (_Float16)(x - (float)h);
    }
    *(f16x8*)(C0 + cb) = h0;
    *(f16x8*)(C1 + cb) = h1;
}

// ---------------------------------------------------------------------------
// Activation split: X fp32 [64][K][256] -> 2 fp16 chunk arrays, blocked B
// layout, scaled by 2^8. grid (2, KT, 64), block (128,4): tx = n, ty = k8.
// ---------------------------------------------------------------------------
__global__ void splitB(const float* __restrict__ X,
                       _Float16* __restrict__ C0, _Float16* __restrict__ C1,
                       int KT, float scale)
{
    const int nb = blockIdx.x, kt = blockIdx.y, bt = blockIdx.z;
    const int nn = threadIdx.x, k8 = threadIdx.y;
    const int K = KT * 32;
    const float* src = X + ((size_t)bt * K + kt * 32 + k8 * 8) * 256 + nb * 128 + nn;
    const size_t cb = ((((size_t)bt * 2 + nb) * KT + kt) * 512 + k8 * 128 + nn) * 8;
    f16x8 h0, h1;
#pragma unroll
    for (int j = 0; j < 8; ++j) {
        const float x = src[(size_t)j * 256] * scale;
        const _Float16 h = (_Float16)x;
        h0[j] = h;
        h1[j] = (_Float16)(x - (float)h);
    }
    *(f16x8*)(C0 + cb) = h0;
    *(f16x8*)(C1 + cb) = h1;
}

// ---------------------------------------------------------------------------
// BN + LIF over T, writing spikes straight into blocked fp16 B layout
// (spikes {0,1} are exact in fp16; optional attn multiply for the k path).
// pre: fp32 [64][Cc][256]. BN params at bnp[c0+cl] with row stride Cs.
// grid (2, Cc/32, 16), block (128,4): tx = n, ty = k8. 8 channels/thread.
// ---------------------------------------------------------------------------
__global__ void bnlifB(const float* __restrict__ pre,
                       const float* __restrict__ attn,
                       const float* __restrict__ bnp,
                       int Cc, int Cs, int c0,
                       _Float16* __restrict__ outB, int KT)
{
    const int nb = blockIdx.x, kt = blockIdx.y, b = blockIdx.z;
    const int nn = threadIdx.x, k8 = threadIdx.y;
    const int cl = kt * 32 + k8 * 8;          // local channel base
    const int n = nb * 128 + nn;
    float sc[8], be[8], mu[8];
#pragma unroll
    for (int j = 0; j < 8; ++j) {
        const int c = c0 + cl + j;
        const float g = bnp[c];
        be[j] = bnp[Cs + c];
        mu[j] = bnp[2 * Cs + c];
        const float va = bnp[3 * Cs + c];
        sc[j] = g * rsqrtf(va + 1e-5f);
    }
    float v[8];
#pragma unroll
    for (int j = 0; j < 8; ++j) v[j] = 0.f;
    const int h = cl >> 6;                    // head (k path; c0==0 there)
#pragma unroll
    for (int t = 0; t < T_; ++t) {
        const int bt = t * B_ + b;
        const float* p = pre + ((size_t)bt * Cc + cl) * 256 + n;
        const float av = attn ? attn[((size_t)bt * 12 + h) * 256 + n] : 1.f;
        f16x8 s;
#pragma unroll
        for (int j = 0; j < 8; ++j) {
            const float u = (p[(size_t)j * 256] - mu[j]) * sc[j] + be[j];
            v[j] = v[j] + (u - v[j]) * 0.5f;            // TAU = 2
            const float sp = (v[j] >= 1.0f) ? 1.0f : 0.0f;
            v[j] = (sp > 0.0f) ? 0.0f : v[j];           // hard reset
            s[j] = (_Float16)(sp * av);
        }
        *(f16x8*)(outB + ((((size_t)bt * 2 + nb) * KT + kt) * 512 + k8 * 128 + nn) * 8) = s;
    }
}

// ---------------------------------------------------------------------------
// fp32 BN + LIF (q spikes and final outputs). Unchanged from round 2.
// ---------------------------------------------------------------------------
__global__ void bnlif_kernel(const float* pre,
                             const float* __restrict__ addin,
                             float* out,
                             const float* __restrict__ bnp, int Cc, int Cs)
{
    const int n = threadIdx.x;
    const int c = blockIdx.x;
    const int b = blockIdx.y;
    const float g  = bnp[c];
    const float be = bnp[Cs + c];
    const float mu = bnp[2 * Cs + c];
    const float va = bnp[3 * Cs + c];
    const float scale = g / sqrtf(va + 1e-5f);
    const size_t base = ((size_t)b * Cc + c) * N_ + n;
    const size_t tstride = (size_t)B_ * Cc * N_;
    float v = 0.0f;
#pragma unroll
    for (int t = 0; t < T_; ++t) {
        const size_t idx = base + (size_t)t * tstride;
        const float u = (pre[idx] - mu) * scale + be;
        v = v + (u - v) * 0.5f;
        const float s = (v >= 1.0f) ? 1.0f : 0.0f;
        float o = s;
        if (addin) o += addin[idx];
        out[idx] = o;
        v = (s > 0.0f) ? 0.0f : v;
    }
}

__global__ void attn_kernel(const float* __restrict__ q, float* __restrict__ attn)
{
    const int n = threadIdx.x;
    const int h = blockIdx.x;
    const int b = blockIdx.y;
    float v = 0.0f;
#pragma unroll
    for (int t = 0; t < T_; ++t) {
        const float* qp = q + (((size_t)(t * B_ + b) * C_) + h * 64) * N_ + n;
        float s = 0.0f;
#pragma unroll 8
        for (int d = 0; d < 64; ++d) s += qp[(size_t)d * N_];
        v = v + (s - v) * 0.5f;
        const float sp = (v >= 1.0f) ? 1.0f : 0.0f;
        attn[((size_t)(t * B_ + b) * 12 + h) * N_ + n] = sp;
        v = (sp > 0.0f) ? 0.0f : v;
    }
}

extern "C" void kernel_launch(void* const* d_in, const int* in_sizes, int n_in,
                              void* d_out, int out_size, void* d_ws, size_t ws_size,
                              hipStream_t stream) {
    const float* x    = (const float*)d_in[0];
    const float* w_q  = (const float*)d_in[1];
    const float* bn_q = (const float*)d_in[2];
    const float* w_k  = (const float*)d_in[3];
    const float* bn_k = (const float*)d_in[4];
    const float* w_p  = (const float*)d_in[5];
    const float* b_p  = (const float*)d_in[6];
    const float* bn_p = (const float*)d_in[7];
    const float* w1   = (const float*)d_in[8];
    const float* b1   = (const float*)d_in[9];
    const float* bn1  = (const float*)d_in[10];
    const float* w2   = (const float*)d_in[11];
    const float* b2   = (const float*)d_in[12];
    const float* bn2  = (const float*)d_in[13];

    const size_t SZ1 = (size_t)T_ * B_ * C_ * N_;     // 12,582,912
    const size_t SZA = (size_t)T_ * B_ * 12 * N_;     // 196,608
    const size_t WCC = (size_t)C_ * C_;               // 589,824
    const size_t WCH = (size_t)C_ * CH_;              // 2,359,296
    const size_t S1B = (size_t)64 * 2 * 12 * 512 * 8; // 6,291,456 halfs

    // Workspace layout (~165.2 MB):
    char* w = (char*)d_ws;
    float*     qbuf  = (float*)w;     w += SZ1 * 4;        // q_pre -> p_pre -> y
    float*     attnb = (float*)w;     w += SZA * 4;        // attn spikes (fp32)
    float*     z1mc  = (float*)w;     w += (SZ1 / 2) * 4;  // z1 chunk [64][384][256]
    _Float16*  R1    = (_Float16*)w;  w += SZ1 * 2 * 2;    // XB0/XB1 -> aB -> YB0/YB1
    _Float16*  WQ0   = (_Float16*)w;  w += WCC * 2;
    _Float16*  WQ1   = (_Float16*)w;  w += WCC * 2;
    _Float16*  WK0   = (_Float16*)w;  w += WCC * 2;
    _Float16*  WK1   = (_Float16*)w;  w += WCC * 2;
    _Float16*  WP0   = (_Float16*)w;  w += WCC * 2;
    _Float16*  WP1   = (_Float16*)w;  w += WCC * 2;
    _Float16*  W10   = (_Float16*)w;  w += WCH * 2;
    _Float16*  W11   = (_Float16*)w;  w += WCH * 2;
    _Float16*  W20   = (_Float16*)w;  w += WCH * 2;
    _Float16*  W21   = (_Float16*)w;  w += WCH * 2;
    _Float16*  s1Bc  = (_Float16*)w;  w += S1B * 2;

    _Float16* XB0 = R1;
    _Float16* XB1 = R1 + SZ1;
    _Float16* aB  = R1;               // overwrites XB0 after q/k GEMMs
    _Float16* YB0 = R1;               // overwrites aB after p GEMM
    _Float16* YB1 = R1 + SZ1;

    float* dob = (float*)d_out;       // k_pre -> (consumed) -> z2 accum -> out

    const float WS = 4096.f;          // 2^12 weight scale
    const float XS = 256.f;           // 2^8 activation scale
    const float OS_G = 1.f / 1048576.f; // 2^-20 (general)
    const float OS_S = 1.f / 4096.f;    // 2^-12 (spike)

    const dim3 blk256(256);
    const dim3 blkS(128, 4);

    // --- weight & input splits ---
    splitW<<<dim3(6, 24),  blkS, 0, stream>>>(w_q, C_,  WQ0, WQ1, 24, WS);
    splitW<<<dim3(6, 24),  blkS, 0, stream>>>(w_k, C_,  WK0, WK1, 24, WS);
    splitW<<<dim3(6, 24),  blkS, 0, stream>>>(w_p, C_,  WP0, WP1, 24, WS);
    splitW<<<dim3(24, 24), blkS, 0, stream>>>(w1,  C_,  W10, W11, 24, WS);
    splitW<<<dim3(6, 96),  blkS, 0, stream>>>(w2,  CH_, W20, W21, 96, WS);
    splitB<<<dim3(2, 24, 64), blkS, 0, stream>>>(x, XB0, XB1, 24, XS);

    // --- q/k GEMMs (general, 3 terms) ---
    gemm_mfma<2><<<dim3(2, 6, 64), blk256, 0, stream>>>(
        WQ0, WQ1, XB0, XB1, qbuf, C_, nullptr, 0, OS_G, 24, 0, 0, 24, 24);
    gemm_mfma<2><<<dim3(2, 6, 64), blk256, 0, stream>>>(
        WK0, WK1, XB0, XB1, dob, C_, nullptr, 0, OS_G, 24, 0, 0, 24, 24);

    // --- q spikes (fp32), attn, then a = attn*k_spike into blocked fp16 ---
    bnlif_kernel<<<dim3(C_, B_), blk256, 0, stream>>>(qbuf, nullptr, qbuf, bn_q, C_, C_);
    attn_kernel<<<dim3(12, B_), blk256, 0, stream>>>(qbuf, attnb);
    bnlifB<<<dim3(2, 24, B_), blkS, 0, stream>>>(dob, attnb, bn_k, C_, C_, 0, aB, 24);

    // --- p = w_p @ a + b_p (spike, 2 terms) -> y = x + spike(bn_p(p)) ---
    gemm_mfma<1><<<dim3(2, 6, 64), blk256, 0, stream>>>(
        WP0, WP1, aB, nullptr, qbuf, C_, b_p, 0, OS_S, 24, 0, 0, 24, 24);
    bnlif_kernel<<<dim3(C_, B_), blk256, 0, stream>>>(qbuf, x, qbuf, bn_p, C_, C_);

    // --- MLP: split y, then 8 chunks of 384 hidden channels ---
    splitB<<<dim3(2, 24, 64), blkS, 0, stream>>>(qbuf, YB0, YB1, 24, XS);
    for (int mc = 0; mc < 8; ++mc) {
        gemm_mfma<2><<<dim3(2, 3, 64), blk256, 0, stream>>>(
            W10, W11, YB0, YB1, z1mc, 384, b1 + 384 * mc, 0, OS_G, 24, 0, 3 * mc, 24, 24);
        bnlifB<<<dim3(2, 12, B_), blkS, 0, stream>>>(
            z1mc, nullptr, bn1, 384, CH_, 384 * mc, s1Bc, 12);
        gemm_mfma<1><<<dim3(2, 6, 64), blk256, 0, stream>>>(
            W20, W21, s1Bc, nullptr, dob, C_, (mc == 0) ? b2 : nullptr, mc > 0 ? 1 : 0,
            OS_S, 96, 12 * mc, 0, 12, 12);
    }

    // --- out = y + spike(bn2(z2)) ---
    bnlif_kernel<<<dim3(C_, B_), blk256, 0, stream>>>(dob, qbuf, dob, bn2, C_, C_);
}

// Round 4
// 1034.319 us; speedup vs baseline: 2.8755x; 1.1662x over previous
//
#include <hip/hip_runtime.h>

// T=4, B=16, C=768, H=W=16 -> N=256, Ch=3072, heads=12, d=64
#define T_ 4
#define B_ 16
#define C_ 768
#define N_ 256
#define CH_ 3072

typedef _Float16 f16x8 __attribute__((ext_vector_type(8)));
typedef float f32x4 __attribute__((ext_vector_type(4)));

// ---------------------------------------------------------------------------
// Blocked operand layout (A=weights, B=activations):
//   per 128(row) x 32(k) tile: 512 chunks of 8 halfs (16B).
//   chunk index c = k8*128 + row; chunk holds k = kt*32 + k8*8 + (0..7).
// A arrays: [mb][KT][512]; B arrays: [bt][nb(2)][KT][512].
// Staging is lane-linear (global_load_lds-compatible) and frag ds_read_b128
// is bank-optimal.
// ---------------------------------------------------------------------------

__device__ __forceinline__ void stage_tile(const _Float16* g, _Float16* l,
                                           int wv, int ln)
{
#pragma unroll
    for (int i = 0; i < 2; ++i) {
        const int c = wv * 128 + i * 64;
        __builtin_amdgcn_global_load_lds(
            (const __attribute__((address_space(1))) void*)(g + (size_t)(c + ln) * 8),
            (__attribute__((address_space(3))) void*)(l + (size_t)c * 8),
            16, 0, 0);
    }
}

// ---------------------------------------------------------------------------
// MFMA GEMM: O[bt, m, n] = oscale * sum_k (A0+A1)[m,k] * (B0[+B1])[k,n] (+bias)
// NB=2: general fp32 operand (A0B0, A0B1, A1B0); NB=1: exact spikes (A0B0, A1B0)
// Tile 128x128, 4 waves of 64x64 (4x4 mfma_f32_16x16x32_f16).
// Dual output: by < splitBy -> Oq, else Ok (m rebased). M = rows per output.
// ---------------------------------------------------------------------------
template <int NB>
__global__ __launch_bounds__(256) void gemm_mfma(
    const _Float16* __restrict__ A0, const _Float16* __restrict__ A1,
    const _Float16* __restrict__ B0, const _Float16* __restrict__ B1,
    float* __restrict__ Oq, float* __restrict__ Ok, int splitBy, int M,
    const float* __restrict__ bias, int accumulate, float oscale,
    int KTA, int ktA0, int mbA0, int KTB, int nkt)
{
    const int nb = blockIdx.x;            // n block (0..1)
    const int by = blockIdx.y;            // output m block
    const int bt = blockIdx.z;            // batch (t*16+b)
    const int mbA = mbA0 + by;

    __shared__ _Float16 lds[(2 + NB) * 4096];

    const int tid = threadIdx.x;
    const int wv = tid >> 6;
    const int ln = tid & 63;
    const int mw = (wv >> 1) * 64;
    const int nw = (wv & 1) * 64;

    f32x4 acc[4][4];
#pragma unroll
    for (int i = 0; i < 4; ++i)
#pragma unroll
        for (int j = 0; j < 4; ++j)
            acc[i][j] = (f32x4){0.f, 0.f, 0.f, 0.f};

    const _Float16* ga0 = A0 + ((size_t)mbA * KTA + ktA0) * 4096;
    const _Float16* ga1 = A1 + ((size_t)mbA * KTA + ktA0) * 4096;
    const _Float16* gb0 = B0 + (((size_t)bt * 2 + nb) * KTB) * 4096;
    const _Float16* gb1 = (NB == 2) ? B1 + (((size_t)bt * 2 + nb) * KTB) * 4096 : nullptr;

    const int ca = (ln >> 4) * 128 + mw + (ln & 15);   // A frag chunk base
    const int cb = (ln >> 4) * 128 + nw + (ln & 15);   // B frag chunk base

    for (int kt = 0; kt < nkt; ++kt) {
        __syncthreads();   // protect previous iteration's LDS frag reads
        stage_tile(ga0, &lds[0], wv, ln);
        stage_tile(ga1, &lds[4096], wv, ln);
        stage_tile(gb0, &lds[2 * 4096], wv, ln);
        if (NB == 2) stage_tile(gb1, &lds[3 * 4096], wv, ln);
        __syncthreads();   // compiler drains vmcnt before barrier

        f16x8 a0[4], a1[4];
#pragma unroll
        for (int mt = 0; mt < 4; ++mt) {
            a0[mt] = *(const f16x8*)&lds[(ca + mt * 16) * 8];
            a1[mt] = *(const f16x8*)&lds[4096 + (ca + mt * 16) * 8];
        }
#pragma unroll
        for (int nt = 0; nt < 4; ++nt) {
            const f16x8 b0 = *(const f16x8*)&lds[2 * 4096 + (cb + nt * 16) * 8];
            f16x8 b1;
            if (NB == 2) b1 = *(const f16x8*)&lds[3 * 4096 + (cb + nt * 16) * 8];
#pragma unroll
            for (int mt = 0; mt < 4; ++mt) {
                acc[mt][nt] = __builtin_amdgcn_mfma_f32_16x16x32_f16(a0[mt], b0, acc[mt][nt], 0, 0, 0);
                acc[mt][nt] = __builtin_amdgcn_mfma_f32_16x16x32_f16(a1[mt], b0, acc[mt][nt], 0, 0, 0);
                if (NB == 2)
                    acc[mt][nt] = __builtin_amdgcn_mfma_f32_16x16x32_f16(a0[mt], b1, acc[mt][nt], 0, 0, 0);
            }
        }
        ga0 += 4096; ga1 += 4096; gb0 += 4096;
        if (NB == 2) gb1 += 4096;
    }

    // Epilogue. C/D layout: col(n) = lane&15, row(m) = (lane>>4)*4 + reg.
    float* Obase = (by < splitBy) ? Oq : Ok;
    const int byl = (by < splitBy) ? by : by - splitBy;
    float* Ob = Obase + (size_t)bt * M * 256;
    const int lm = (ln >> 4) * 4;
    const int lnn = ln & 15;
#pragma unroll
    for (int mt = 0; mt < 4; ++mt) {
#pragma unroll
        for (int r = 0; r < 4; ++r) {
            const int m = byl * 128 + mw + mt * 16 + lm + r;
            const float bb = bias ? bias[m] : 0.0f;
#pragma unroll
            for (int nt = 0; nt < 4; ++nt) {
                const int n = nb * 128 + nw + nt * 16 + lnn;
                float* op = Ob + (size_t)m * 256 + n;
                float v = acc[mt][nt][r] * oscale;
                v += accumulate ? *op : bb;
                *op = v;
            }
        }
    }
}

// ---------------------------------------------------------------------------
// Weight split: W fp32 [M][ldW] -> 2 fp16 chunk arrays (blocked A layout),
// scaled by 2^12. grid (M/128, KT), block (128,4).
// ---------------------------------------------------------------------------
__global__ void splitW(const float* __restrict__ W, int ldW,
                       _Float16* __restrict__ C0, _Float16* __restrict__ C1,
                       int KT, float scale)
{
    const int mb = blockIdx.x, kt = blockIdx.y;
    const int mm = threadIdx.x, k8 = threadIdx.y;
    const float* src = W + (size_t)(mb * 128 + mm) * ldW + kt * 32 + k8 * 8;
    const size_t cb = (((size_t)mb * KT + kt) * 512 + k8 * 128 + mm) * 8;
    f16x8 h0, h1;
#pragma unroll
    for (int j = 0; j < 8; ++j) {
        const float x = src[j] * scale;
        const _Float16 h = (_Float16)x;
        h0[j] = h;
        h1[j] = (_Float16)(x - (float)h);
    }
    *(f16x8*)(C0 + cb) = h0;
    *(f16x8*)(C1 + cb) = h1;
}

// ---------------------------------------------------------------------------
// Activation split: X fp32 [64][K][256] -> 2 fp16 chunk arrays (blocked B),
// scaled by 2^8. grid (2, KT, 64), block (128,4).
// ---------------------------------------------------------------------------
__global__ void splitB(const float* __restrict__ X,
                       _Float16* __restrict__ C0, _Float16* __restrict__ C1,
                       int KT, float scale)
{
    const int nb = blockIdx.x, kt = blockIdx.y, bt = blockIdx.z;
    const int nn = threadIdx.x, k8 = threadIdx.y;
    const int K = KT * 32;
    const float* src = X + ((size_t)bt * K + kt * 32 + k8 * 8) * 256 + nb * 128 + nn;
    const size_t cb = ((((size_t)bt * 2 + nb) * KT + kt) * 512 + k8 * 128 + nn) * 8;
    f16x8 h0, h1;
#pragma unroll
    for (int j = 0; j < 8; ++j) {
        const float x = src[(size_t)j * 256] * scale;
        const _Float16 h = (_Float16)x;
        h0[j] = h;
        h1[j] = (_Float16)(x - (float)h);
    }
    *(f16x8*)(C0 + cb) = h0;
    *(f16x8*)(C1 + cb) = h1;
}

// ---------------------------------------------------------------------------
// Fused q path: BN+LIF on q_pre, head-sum over d=64, attn LIF -> attn spikes.
// q spikes never materialized. grid (4, 12, 16) = (n-block, h, b),
// block (64, 8): tx = n lane, ty = d-octet.
// ---------------------------------------------------------------------------
__global__ __launch_bounds__(512) void qattn_kernel(
    const float* __restrict__ qpre, const float* __restrict__ bnp,
    float* __restrict__ attn)
{
    const int tx = threadIdx.x, ty = threadIdx.y;
    const int n = blockIdx.x * 64 + tx;
    const int h = blockIdx.y, b = blockIdx.z;
    __shared__ float red[8][64];

    float sc[8], be[8], mu[8];
#pragma unroll
    for (int j = 0; j < 8; ++j) {
        const int c = h * 64 + ty * 8 + j;
        const float g = bnp[c];
        be[j] = bnp[C_ + c];
        mu[j] = bnp[2 * C_ + c];
        sc[j] = g * rsqrtf(bnp[3 * C_ + c] + 1e-5f);
    }
    float v[8];
#pragma unroll
    for (int j = 0; j < 8; ++j) v[j] = 0.f;
    float va = 0.f;

#pragma unroll
    for (int t = 0; t < T_; ++t) {
        const int bt = t * B_ + b;
        const float* p = qpre + ((size_t)bt * C_ + h * 64 + ty * 8) * 256 + n;
        float s = 0.f;
#pragma unroll
        for (int j = 0; j < 8; ++j) {
            const float u = (p[(size_t)j * 256] - mu[j]) * sc[j] + be[j];
            v[j] = v[j] + (u - v[j]) * 0.5f;
            const float sp = (v[j] >= 1.0f) ? 1.0f : 0.0f;
            v[j] = (sp > 0.0f) ? 0.0f : v[j];
            s += sp;
        }
        red[ty][tx] = s;
        __syncthreads();
        if (ty == 0) {
            float tot = red[0][tx];
#pragma unroll
            for (int r = 1; r < 8; ++r) tot += red[r][tx];
            va = va + (tot - va) * 0.5f;
            const float asp = (va >= 1.0f) ? 1.0f : 0.0f;
            va = (asp > 0.0f) ? 0.0f : va;
            attn[((size_t)bt * 12 + h) * 256 + n] = asp;
        }
        __syncthreads();
    }
}

// ---------------------------------------------------------------------------
// BN + LIF over T -> spikes straight into blocked fp16 B layout
// (optional attn multiply for the k path). grid (2, Cc/32, 16), block (128,4).
// ---------------------------------------------------------------------------
__global__ void bnlifB(const float* __restrict__ pre,
                       const float* __restrict__ attn,
                       const float* __restrict__ bnp,
                       int Cc, int Cs, int c0,
                       _Float16* __restrict__ outB, int KT)
{
    const int nb = blockIdx.x, kt = blockIdx.y, b = blockIdx.z;
    const int nn = threadIdx.x, k8 = threadIdx.y;
    const int cl = kt * 32 + k8 * 8;
    const int n = nb * 128 + nn;
    float sc[8], be[8], mu[8];
#pragma unroll
    for (int j = 0; j < 8; ++j) {
        const int c = c0 + cl + j;
        const float g = bnp[c];
        be[j] = bnp[Cs + c];
        mu[j] = bnp[2 * Cs + c];
        sc[j] = g * rsqrtf(bnp[3 * Cs + c] + 1e-5f);
    }
    float v[8];
#pragma unroll
    for (int j = 0; j < 8; ++j) v[j] = 0.f;
    const int h = cl >> 6;
#pragma unroll
    for (int t = 0; t < T_; ++t) {
        const int bt = t * B_ + b;
        const float* p = pre + ((size_t)bt * Cc + cl) * 256 + n;
        const float av = attn ? attn[((size_t)bt * 12 + h) * 256 + n] : 1.f;
        f16x8 s;
#pragma unroll
        for (int j = 0; j < 8; ++j) {
            const float u = (p[(size_t)j * 256] - mu[j]) * sc[j] + be[j];
            v[j] = v[j] + (u - v[j]) * 0.5f;
            const float sp = (v[j] >= 1.0f) ? 1.0f : 0.0f;
            v[j] = (sp > 0.0f) ? 0.0f : v[j];
            s[j] = (_Float16)(sp * av);
        }
        *(f16x8*)(outB + ((((size_t)bt * 2 + nb) * KT + kt) * 512 + k8 * 128 + nn) * 8) = s;
    }
}

// ---------------------------------------------------------------------------
// Fused y path: y = x + spike(bn_p(p_pre)), writing y fp32 (in-place on p_pre)
// AND the scaled fp16 2-chunk blocked split of y. grid (2, 24, 16), blk(128,4).
// ---------------------------------------------------------------------------
__global__ void bnlif_y_split(float* ppre, const float* __restrict__ x,
                              const float* __restrict__ bnp,
                              _Float16* __restrict__ Y0, _Float16* __restrict__ Y1,
                              float xscale)
{
    const int nb = blockIdx.x, kt = blockIdx.y, b = blockIdx.z;
    const int nn = threadIdx.x, k8 = threadIdx.y;
    const int cl = kt * 32 + k8 * 8;
    const int n = nb * 128 + nn;
    float sc[8], be[8], mu[8];
#pragma unroll
    for (int j = 0; j < 8; ++j) {
        const int c = cl + j;
        const float g = bnp[c];
        be[j] = bnp[C_ + c];
        mu[j] = bnp[2 * C_ + c];
        sc[j] = g * rsqrtf(bnp[3 * C_ + c] + 1e-5f);
    }
    float v[8];
#pragma unroll
    for (int j = 0; j < 8; ++j) v[j] = 0.f;
#pragma unroll
    for (int t = 0; t < T_; ++t) {
        const int bt = t * B_ + b;
        const size_t off = ((size_t)bt * C_ + cl) * 256 + n;
        float* p = ppre + off;
        const float* xx = x + off;
        f16x8 h0, h1;
#pragma unroll
        for (int j = 0; j < 8; ++j) {
            const float u = (p[(size_t)j * 256] - mu[j]) * sc[j] + be[j];
            v[j] = v[j] + (u - v[j]) * 0.5f;
            const float sp = (v[j] >= 1.0f) ? 1.0f : 0.0f;
            v[j] = (sp > 0.0f) ? 0.0f : v[j];
            const float y = xx[(size_t)j * 256] + sp;
            p[(size_t)j * 256] = y;                    // y fp32 (in-place)
            const float ys = y * xscale;
            const _Float16 hh = (_Float16)ys;
            h0[j] = hh;
            h1[j] = (_Float16)(ys - (float)hh);
        }
        const size_t cb = ((((size_t)bt * 2 + nb) * 24 + kt) * 512 + k8 * 128 + nn) * 8;
        *(f16x8*)(Y0 + cb) = h0;
        *(f16x8*)(Y1 + cb) = h1;
    }
}

// ---------------------------------------------------------------------------
// fp32 BN + LIF (final output stage).
// ---------------------------------------------------------------------------
__global__ void bnlif_kernel(const float* pre,
                             const float* __restrict__ addin,
                             float* out,
                             const float* __restrict__ bnp, int Cc, int Cs)
{
    const int n = threadIdx.x;
    const int c = blockIdx.x;
    const int b = blockIdx.y;
    const float g  = bnp[c];
    const float be = bnp[Cs + c];
    const float mu = bnp[2 * Cs + c];
    const float va = bnp[3 * Cs + c];
    const float scale = g / sqrtf(va + 1e-5f);
    const size_t base = ((size_t)b * Cc + c) * N_ + n;
    const size_t tstride = (size_t)B_ * Cc * N_;
    float v = 0.0f;
#pragma unroll
    for (int t = 0; t < T_; ++t) {
        const size_t idx = base + (size_t)t * tstride;
        const float u = (pre[idx] - mu) * scale + be;
        v = v + (u - v) * 0.5f;
        const float s = (v >= 1.0f) ? 1.0f : 0.0f;
        float o = s;
        if (addin) o += addin[idx];
        out[idx] = o;
        v = (s > 0.0f) ? 0.0f : v;
    }
}

extern "C" void kernel_launch(void* const* d_in, const int* in_sizes, int n_in,
                              void* d_out, int out_size, void* d_ws, size_t ws_size,
                              hipStream_t stream) {
    const float* x    = (const float*)d_in[0];
    const float* w_q  = (const float*)d_in[1];
    const float* bn_q = (const float*)d_in[2];
    const float* w_k  = (const float*)d_in[3];
    const float* bn_k = (const float*)d_in[4];
    const float* w_p  = (const float*)d_in[5];
    const float* b_p  = (const float*)d_in[6];
    const float* bn_p = (const float*)d_in[7];
    const float* w1   = (const float*)d_in[8];
    const float* b1   = (const float*)d_in[9];
    const float* bn1  = (const float*)d_in[10];
    const float* w2   = (const float*)d_in[11];
    const float* b2   = (const float*)d_in[12];
    const float* bn2  = (const float*)d_in[13];

    const size_t SZ1 = (size_t)T_ * B_ * C_ * N_;     // 12,582,912
    const size_t SZA = (size_t)T_ * B_ * 12 * N_;     // 196,608
    const size_t WCC = (size_t)C_ * C_;               // 589,824
    const size_t WCH = (size_t)C_ * CH_;              // 2,359,296

    // --- workspace layout (fixed part ~127.4 MB, flex part sized by ws) ---
    char* w = (char*)d_ws;
    float*     qbuf  = (float*)w;     w += SZ1 * 4;      // q_pre -> p_pre -> y
    float*     attnb = (float*)w;     w += SZA * 4;
    _Float16*  R1    = (_Float16*)w;  w += SZ1 * 4;      // XB0/XB1 -> aB -> YB0/YB1
    _Float16*  WQK0  = (_Float16*)w;  w += WCC * 2 * 2;  // [wq; wk] chunk0
    _Float16*  WQK1  = (_Float16*)w;  w += WCC * 2 * 2;
    _Float16*  WP0   = (_Float16*)w;  w += WCC * 2;
    _Float16*  WP1   = (_Float16*)w;  w += WCC * 2;
    _Float16*  W10   = (_Float16*)w;  w += WCH * 2;
    _Float16*  W11   = (_Float16*)w;  w += WCH * 2;
    _Float16*  W20   = (_Float16*)w;  w += WCH * 2;
    _Float16*  W21   = (_Float16*)w;  w += WCH * 2;
    float*     z1mc  = (float*)w;                        // flex: z1 chunk fp32
    const size_t fixed = (size_t)(w - (char*)d_ws);

    // MLP chunking: 4 chunks of 768 if workspace allows, else 8 of 384.
    // (deterministic per session: ws_size constant -> graph-safe)
    int nchunk = 4;
    {
        const size_t need4 = fixed + ((size_t)768 * 64 * 256) * 4   // z1mc
                                   + ((size_t)64 * 2 * 24 * 4096) * 2;  // s1Bc
        if (ws_size < need4) nchunk = 8;
    }
    const int chunkM = CH_ / nchunk;        // 768 or 384
    const int mbC = chunkM / 128;           // 6 or 3
    const int KTc = chunkM / 32;            // 24 or 12
    _Float16* s1Bc = (_Float16*)((char*)z1mc + (size_t)chunkM * 64 * 256 * 4);

    _Float16* XB0 = R1;
    _Float16* XB1 = R1 + SZ1;
    _Float16* aB  = R1;                     // after q/k GEMMs
    _Float16* YB0 = R1;                     // after p GEMM
    _Float16* YB1 = R1 + SZ1;

    float* dob = (float*)d_out;             // k_pre -> (consumed) -> z2 -> out

    const float WS = 4096.f;                // 2^12
    const float XS = 256.f;                 // 2^8
    const float OS_G = 1.f / 1048576.f;     // 2^-20
    const float OS_S = 1.f / 4096.f;        // 2^-12

    const dim3 blk256(256);
    const dim3 blkS(128, 4);

    // --- weight & input splits ---
    splitW<<<dim3(6, 24),  blkS, 0, stream>>>(w_q, C_,  WQK0,       WQK1,       24, WS);
    splitW<<<dim3(6, 24),  blkS, 0, stream>>>(w_k, C_,  WQK0 + WCC, WQK1 + WCC, 24, WS);
    splitW<<<dim3(6, 24),  blkS, 0, stream>>>(w_p, C_,  WP0, WP1, 24, WS);
    splitW<<<dim3(24, 24), blkS, 0, stream>>>(w1,  C_,  W10, W11, 24, WS);
    splitW<<<dim3(6, 96),  blkS, 0, stream>>>(w2,  CH_, W20, W21, 96, WS);
    splitB<<<dim3(2, 24, 64), blkS, 0, stream>>>(x, XB0, XB1, 24, XS);

    // --- merged q+k GEMM (general, 3 terms): by 0..5 -> qbuf, 6..11 -> dob ---
    gemm_mfma<2><<<dim3(2, 12, 64), blk256, 0, stream>>>(
        WQK0, WQK1, XB0, XB1, qbuf, dob, 6, C_, nullptr, 0, OS_G, 24, 0, 0, 24, 24);

    // --- fused q->attn; k spikes * attn into blocked fp16 ---
    qattn_kernel<<<dim3(4, 12, B_), dim3(64, 8), 0, stream>>>(qbuf, bn_q, attnb);
    bnlifB<<<dim3(2, 24, B_), blkS, 0, stream>>>(dob, attnb, bn_k, C_, C_, 0, aB, 24);

    // --- p = w_p @ a + b_p (spike, 2 terms); y = x + spike(bn_p(p)) + split ---
    gemm_mfma<1><<<dim3(2, 6, 64), blk256, 0, stream>>>(
        WP0, WP1, aB, nullptr, qbuf, nullptr, 9999, C_, b_p, 0, OS_S, 24, 0, 0, 24, 24);
    bnlif_y_split<<<dim3(2, 24, B_), blkS, 0, stream>>>(qbuf, x, bn_p, YB0, YB1, XS);

    // --- MLP chunks ---
    for (int mc = 0; mc < nchunk; ++mc) {
        gemm_mfma<2><<<dim3(2, mbC, 64), blk256, 0, stream>>>(
            W10, W11, YB0, YB1, z1mc, nullptr, 9999, chunkM,
            b1 + chunkM * mc, 0, OS_G, 24, 0, mbC * mc, 24, 24);
        bnlifB<<<dim3(2, KTc, B_), blkS, 0, stream>>>(
            z1mc, nullptr, bn1, chunkM, CH_, chunkM * mc, s1Bc, KTc);
        gemm_mfma<1><<<dim3(2, 6, 64), blk256, 0, stream>>>(
            W20, W21, s1Bc, nullptr, dob, nullptr, 9999, C_,
            (mc == 0) ? b2 : nullptr, mc > 0 ? 1 : 0, OS_S, 96, KTc * mc, 0, KTc, KTc);
    }

    // --- out = y + spike(bn2(z2)) ---
    bnlif_kernel<<<dim3(C_, B_), blk256, 0, stream>>>(dob, qbuf, dob, bn2, C_, C_);
}

// Round 5
// 968.825 us; speedup vs baseline: 3.0699x; 1.0676x over previous
//
#include <hip/hip_runtime.h>

// T=4, B=16, C=768, H=W=16 -> N=256, Ch=3072, heads=12, d=64
#define T_ 4
#define B_ 16
#define C_ 768
#define N_ 256
#define CH_ 3072

typedef _Float16 f16x8 __attribute__((ext_vector_type(8)));
typedef float f32x4 __attribute__((ext_vector_type(4)));

// ---------------------------------------------------------------------------
// Blocked operand layout (A=weights, B=activations):
//   per 128(row) x 32(k) tile: 512 chunks of 8 halfs (16B).
//   chunk index c = k8*128 + row; chunk holds k = kt*32 + k8*8 + (0..7).
// A arrays: [mb][KT][512]; B arrays: [bt][nb(2)][KT][512].
// Staging is lane-linear (global_load_lds-compatible) and frag ds_read_b128
// is bank-optimal.
// ---------------------------------------------------------------------------

__device__ __forceinline__ void stage_tile(const _Float16* g, _Float16* l,
                                           int wv, int ln)
{
#pragma unroll
    for (int i = 0; i < 2; ++i) {
        const int c = wv * 128 + i * 64;
        __builtin_amdgcn_global_load_lds(
            (const __attribute__((address_space(1))) void*)(g + (size_t)(c + ln) * 8),
            (__attribute__((address_space(3))) void*)(l + (size_t)c * 8),
            16, 0, 0);
    }
}

// ---------------------------------------------------------------------------
// MFMA GEMM: O[bt, m, n] = oscale * sum_k (A0+A1)[m,k] * (B0[+B1])[k,n] (+bias)
// NB=2: general fp32 operand (A0B0, A0B1, A1B0); NB=1: exact spikes (A0B0, A1B0)
// Tile 128x128, 4 waves of 64x64 (4x4 mfma_f32_16x16x32_f16).
// Dual output: by < splitBy -> Oq, else Ok (m rebased). M = rows per output.
// ---------------------------------------------------------------------------
template <int NB>
__global__ __launch_bounds__(256) void gemm_mfma(
    const _Float16* __restrict__ A0, const _Float16* __restrict__ A1,
    const _Float16* __restrict__ B0, const _Float16* __restrict__ B1,
    float* __restrict__ Oq, float* __restrict__ Ok, int splitBy, int M,
    const float* __restrict__ bias, int accumulate, float oscale,
    int KTA, int ktA0, int mbA0, int KTB, int nkt)
{
    const int nb = blockIdx.x;            // n block (0..1)
    const int by = blockIdx.y;            // output m block
    const int bt = blockIdx.z;            // batch (t*16+b)
    const int mbA = mbA0 + by;

    __shared__ _Float16 lds[(2 + NB) * 4096];

    const int tid = threadIdx.x;
    const int wv = tid >> 6;
    const int ln = tid & 63;
    const int mw = (wv >> 1) * 64;
    const int nw = (wv & 1) * 64;

    f32x4 acc[4][4];
#pragma unroll
    for (int i = 0; i < 4; ++i)
#pragma unroll
        for (int j = 0; j < 4; ++j)
            acc[i][j] = (f32x4){0.f, 0.f, 0.f, 0.f};

    const _Float16* ga0 = A0 + ((size_t)mbA * KTA + ktA0) * 4096;
    const _Float16* ga1 = A1 + ((size_t)mbA * KTA + ktA0) * 4096;
    const _Float16* gb0 = B0 + (((size_t)bt * 2 + nb) * KTB) * 4096;
    const _Float16* gb1 = (NB == 2) ? B1 + (((size_t)bt * 2 + nb) * KTB) * 4096 : nullptr;

    const int ca = (ln >> 4) * 128 + mw + (ln & 15);   // A frag chunk base
    const int cb = (ln >> 4) * 128 + nw + (ln & 15);   // B frag chunk base

    for (int kt = 0; kt < nkt; ++kt) {
        __syncthreads();   // protect previous iteration's LDS frag reads
        stage_tile(ga0, &lds[0], wv, ln);
        stage_tile(ga1, &lds[4096], wv, ln);
        stage_tile(gb0, &lds[2 * 4096], wv, ln);
        if (NB == 2) stage_tile(gb1, &lds[3 * 4096], wv, ln);
        __syncthreads();   // compiler drains vmcnt before barrier

        f16x8 a0[4], a1[4];
#pragma unroll
        for (int mt = 0; mt < 4; ++mt) {
            a0[mt] = *(const f16x8*)&lds[(ca + mt * 16) * 8];
            a1[mt] = *(const f16x8*)&lds[4096 + (ca + mt * 16) * 8];
        }
#pragma unroll
        for (int nt = 0; nt < 4; ++nt) {
            const f16x8 b0 = *(const f16x8*)&lds[2 * 4096 + (cb + nt * 16) * 8];
            f16x8 b1;
            if (NB == 2) b1 = *(const f16x8*)&lds[3 * 4096 + (cb + nt * 16) * 8];
#pragma unroll
            for (int mt = 0; mt < 4; ++mt) {
                acc[mt][nt] = __builtin_amdgcn_mfma_f32_16x16x32_f16(a0[mt], b0, acc[mt][nt], 0, 0, 0);
                acc[mt][nt] = __builtin_amdgcn_mfma_f32_16x16x32_f16(a1[mt], b0, acc[mt][nt], 0, 0, 0);
                if (NB == 2)
                    acc[mt][nt] = __builtin_amdgcn_mfma_f32_16x16x32_f16(a0[mt], b1, acc[mt][nt], 0, 0, 0);
            }
        }
        ga0 += 4096; ga1 += 4096; gb0 += 4096;
        if (NB == 2) gb1 += 4096;
    }

    // Epilogue. C/D layout: col(n) = lane&15, row(m) = (lane>>4)*4 + reg.
    float* Obase = (by < splitBy) ? Oq : Ok;
    const int byl = (by < splitBy) ? by : by - splitBy;
    float* Ob = Obase + (size_t)bt * M * 256;
    const int lm = (ln >> 4) * 4;
    const int lnn = ln & 15;
#pragma unroll
    for (int mt = 0; mt < 4; ++mt) {
#pragma unroll
        for (int r = 0; r < 4; ++r) {
            const int m = byl * 128 + mw + mt * 16 + lm + r;
            const float bb = bias ? bias[m] : 0.0f;
#pragma unroll
            for (int nt = 0; nt < 4; ++nt) {
                const int n = nb * 128 + nw + nt * 16 + lnn;
                float* op = Ob + (size_t)m * 256 + n;
                float v = acc[mt][nt][r] * oscale;
                v += accumulate ? *op : bb;
                *op = v;
            }
        }
    }
}

// ---------------------------------------------------------------------------
// Weight split: W fp32 [M][ldW] -> 2 fp16 chunk arrays (blocked A layout),
// scaled by 2^12. grid (M/128, KT), block (128,4).
// ---------------------------------------------------------------------------
__global__ void splitW(const float* __restrict__ W, int ldW,
                       _Float16* __restrict__ C0, _Float16* __restrict__ C1,
                       int KT, float scale)
{
    const int mb = blockIdx.x, kt = blockIdx.y;
    const int mm = threadIdx.x, k8 = threadIdx.y;
    const float* src = W + (size_t)(mb * 128 + mm) * ldW + kt * 32 + k8 * 8;
    const size_t cb = (((size_t)mb * KT + kt) * 512 + k8 * 128 + mm) * 8;
    f16x8 h0, h1;
#pragma unroll
    for (int j = 0; j < 8; ++j) {
        const float x = src[j] * scale;
        const _Float16 h = (_Float16)x;
        h0[j] = h;
        h1[j] = (_Float16)(x - (float)h);
    }
    *(f16x8*)(C0 + cb) = h0;
    *(f16x8*)(C1 + cb) = h1;
}

// ---------------------------------------------------------------------------
// Merged split of the three CxC weights: z=0 -> w_q (WQK rows 0..767),
// z=1 -> w_k (WQK rows 768..1535), z=2 -> w_p. grid (6, 24, 3), block (128,4).
// ---------------------------------------------------------------------------
__global__ void splitW3(const float* __restrict__ wq, const float* __restrict__ wk,
                        const float* __restrict__ wp,
                        _Float16* __restrict__ WQK0, _Float16* __restrict__ WQK1,
                        _Float16* __restrict__ WP0,  _Float16* __restrict__ WP1,
                        float scale)
{
    const size_t WCC = (size_t)C_ * C_;
    const int z = blockIdx.z;
    const float* W;
    _Float16 *C0, *C1;
    if (z == 0)      { W = wq; C0 = WQK0;       C1 = WQK1; }
    else if (z == 1) { W = wk; C0 = WQK0 + WCC; C1 = WQK1 + WCC; }
    else             { W = wp; C0 = WP0;        C1 = WP1; }
    const int mb = blockIdx.x, kt = blockIdx.y;
    const int mm = threadIdx.x, k8 = threadIdx.y;
    const float* src = W + (size_t)(mb * 128 + mm) * C_ + kt * 32 + k8 * 8;
    const size_t cb = (((size_t)mb * 24 + kt) * 512 + k8 * 128 + mm) * 8;
    f16x8 h0, h1;
#pragma unroll
    for (int j = 0; j < 8; ++j) {
        const float x = src[j] * scale;
        const _Float16 h = (_Float16)x;
        h0[j] = h;
        h1[j] = (_Float16)(x - (float)h);
    }
    *(f16x8*)(C0 + cb) = h0;
    *(f16x8*)(C1 + cb) = h1;
}

// ---------------------------------------------------------------------------
// Activation split: X fp32 [64][K][256] -> 2 fp16 chunk arrays (blocked B),
// scaled by 2^8. grid (2, KT, 64), block (128,4).
// ---------------------------------------------------------------------------
__global__ void splitB(const float* __restrict__ X,
                       _Float16* __restrict__ C0, _Float16* __restrict__ C1,
                       int KT, float scale)
{
    const int nb = blockIdx.x, kt = blockIdx.y, bt = blockIdx.z;
    const int nn = threadIdx.x, k8 = threadIdx.y;
    const int K = KT * 32;
    const float* src = X + ((size_t)bt * K + kt * 32 + k8 * 8) * 256 + nb * 128 + nn;
    const size_t cb = ((((size_t)bt * 2 + nb) * KT + kt) * 512 + k8 * 128 + nn) * 8;
    f16x8 h0, h1;
#pragma unroll
    for (int j = 0; j < 8; ++j) {
        const float x = src[(size_t)j * 256] * scale;
        const _Float16 h = (_Float16)x;
        h0[j] = h;
        h1[j] = (_Float16)(x - (float)h);
    }
    *(f16x8*)(C0 + cb) = h0;
    *(f16x8*)(C1 + cb) = h1;
}

// ---------------------------------------------------------------------------
// Fused q path: BN+LIF on q_pre, head-sum over d=64, attn LIF -> attn spikes.
// q spikes never materialized. grid (4, 12, 16), block (64, 8).
// ---------------------------------------------------------------------------
__global__ __launch_bounds__(512) void qattn_kernel(
    const float* __restrict__ qpre, const float* __restrict__ bnp,
    float* __restrict__ attn)
{
    const int tx = threadIdx.x, ty = threadIdx.y;
    const int n = blockIdx.x * 64 + tx;
    const int h = blockIdx.y, b = blockIdx.z;
    __shared__ float red[8][64];

    float sc[8], be[8], mu[8];
#pragma unroll
    for (int j = 0; j < 8; ++j) {
        const int c = h * 64 + ty * 8 + j;
        const float g = bnp[c];
        be[j] = bnp[C_ + c];
        mu[j] = bnp[2 * C_ + c];
        sc[j] = g * rsqrtf(bnp[3 * C_ + c] + 1e-5f);
    }
    float v[8];
#pragma unroll
    for (int j = 0; j < 8; ++j) v[j] = 0.f;
    float va = 0.f;

#pragma unroll
    for (int t = 0; t < T_; ++t) {
        const int bt = t * B_ + b;
        const float* p = qpre + ((size_t)bt * C_ + h * 64 + ty * 8) * 256 + n;
        float s = 0.f;
#pragma unroll
        for (int j = 0; j < 8; ++j) {
            const float u = (p[(size_t)j * 256] - mu[j]) * sc[j] + be[j];
            v[j] = v[j] + (u - v[j]) * 0.5f;
            const float sp = (v[j] >= 1.0f) ? 1.0f : 0.0f;
            v[j] = (sp > 0.0f) ? 0.0f : v[j];
            s += sp;
        }
        red[ty][tx] = s;
        __syncthreads();
        if (ty == 0) {
            float tot = red[0][tx];
#pragma unroll
            for (int r = 1; r < 8; ++r) tot += red[r][tx];
            va = va + (tot - va) * 0.5f;
            const float asp = (va >= 1.0f) ? 1.0f : 0.0f;
            va = (asp > 0.0f) ? 0.0f : va;
            attn[((size_t)bt * 12 + h) * 256 + n] = asp;
        }
        __syncthreads();
    }
}

// ---------------------------------------------------------------------------
// BN + LIF over T -> spikes straight into blocked fp16 B layout
// (optional attn multiply for the k path). grid (2, Cc/32, 16), block (128,4).
// Output tile index = ktOut0 + kt within a B array of KTout k-tiles.
// ---------------------------------------------------------------------------
__global__ void bnlifB(const float* __restrict__ pre,
                       const float* __restrict__ attn,
                       const float* __restrict__ bnp,
                       int Cc, int Cs, int c0,
                       _Float16* __restrict__ outB, int KTout, int ktOut0)
{
    const int nb = blockIdx.x, kt = blockIdx.y, b = blockIdx.z;
    const int nn = threadIdx.x, k8 = threadIdx.y;
    const int cl = kt * 32 + k8 * 8;
    const int n = nb * 128 + nn;
    float sc[8], be[8], mu[8];
#pragma unroll
    for (int j = 0; j < 8; ++j) {
        const int c = c0 + cl + j;
        const float g = bnp[c];
        be[j] = bnp[Cs + c];
        mu[j] = bnp[2 * Cs + c];
        sc[j] = g * rsqrtf(bnp[3 * Cs + c] + 1e-5f);
    }
    float v[8];
#pragma unroll
    for (int j = 0; j < 8; ++j) v[j] = 0.f;
    const int h = cl >> 6;
#pragma unroll
    for (int t = 0; t < T_; ++t) {
        const int bt = t * B_ + b;
        const float* p = pre + ((size_t)bt * Cc + cl) * 256 + n;
        const float av = attn ? attn[((size_t)bt * 12 + h) * 256 + n] : 1.f;
        f16x8 s;
#pragma unroll
        for (int j = 0; j < 8; ++j) {
            const float u = (p[(size_t)j * 256] - mu[j]) * sc[j] + be[j];
            v[j] = v[j] + (u - v[j]) * 0.5f;
            const float sp = (v[j] >= 1.0f) ? 1.0f : 0.0f;
            v[j] = (sp > 0.0f) ? 0.0f : v[j];
            s[j] = (_Float16)(sp * av);
        }
        *(f16x8*)(outB + ((((size_t)bt * 2 + nb) * KTout + ktOut0 + kt) * 512 + k8 * 128 + nn) * 8) = s;
    }
}

// ---------------------------------------------------------------------------
// Fused y path: y = x + spike(bn_p(p_pre)), writing y fp32 (in-place on p_pre)
// AND the scaled fp16 2-chunk blocked split of y. grid (2, 24, 16), blk(128,4).
// ---------------------------------------------------------------------------
__global__ void bnlif_y_split(float* ppre, const float* __restrict__ x,
                              const float* __restrict__ bnp,
                              _Float16* __restrict__ Y0, _Float16* __restrict__ Y1,
                              float xscale)
{
    const int nb = blockIdx.x, kt = blockIdx.y, b = blockIdx.z;
    const int nn = threadIdx.x, k8 = threadIdx.y;
    const int cl = kt * 32 + k8 * 8;
    const int n = nb * 128 + nn;
    float sc[8], be[8], mu[8];
#pragma unroll
    for (int j = 0; j < 8; ++j) {
        const int c = cl + j;
        const float g = bnp[c];
        be[j] = bnp[C_ + c];
        mu[j] = bnp[2 * C_ + c];
        sc[j] = g * rsqrtf(bnp[3 * C_ + c] + 1e-5f);
    }
    float v[8];
#pragma unroll
    for (int j = 0; j < 8; ++j) v[j] = 0.f;
#pragma unroll
    for (int t = 0; t < T_; ++t) {
        const int bt = t * B_ + b;
        const size_t off = ((size_t)bt * C_ + cl) * 256 + n;
        float* p = ppre + off;
        const float* xx = x + off;
        f16x8 h0, h1;
#pragma unroll
        for (int j = 0; j < 8; ++j) {
            const float u = (p[(size_t)j * 256] - mu[j]) * sc[j] + be[j];
            v[j] = v[j] + (u - v[j]) * 0.5f;
            const float sp = (v[j] >= 1.0f) ? 1.0f : 0.0f;
            v[j] = (sp > 0.0f) ? 0.0f : v[j];
            const float y = xx[(size_t)j * 256] + sp;
            p[(size_t)j * 256] = y;                    // y fp32 (in-place)
            const float ys = y * xscale;
            const _Float16 hh = (_Float16)ys;
            h0[j] = hh;
            h1[j] = (_Float16)(ys - (float)hh);
        }
        const size_t cb = ((((size_t)bt * 2 + nb) * 24 + kt) * 512 + k8 * 128 + nn) * 8;
        *(f16x8*)(Y0 + cb) = h0;
        *(f16x8*)(Y1 + cb) = h1;
    }
}

// ---------------------------------------------------------------------------
// fp32 BN + LIF (final output stage).
// ---------------------------------------------------------------------------
__global__ void bnlif_kernel(const float* pre,
                             const float* __restrict__ addin,
                             float* out,
                             const float* __restrict__ bnp, int Cc, int Cs)
{
    const int n = threadIdx.x;
    const int c = blockIdx.x;
    const int b = blockIdx.y;
    const float g  = bnp[c];
    const float be = bnp[Cs + c];
    const float mu = bnp[2 * Cs + c];
    const float va = bnp[3 * Cs + c];
    const float scale = g / sqrtf(va + 1e-5f);
    const size_t base = ((size_t)b * Cc + c) * N_ + n;
    const size_t tstride = (size_t)B_ * Cc * N_;
    float v = 0.0f;
#pragma unroll
    for (int t = 0; t < T_; ++t) {
        const size_t idx = base + (size_t)t * tstride;
        const float u = (pre[idx] - mu) * scale + be;
        v = v + (u - v) * 0.5f;
        const float s = (v >= 1.0f) ? 1.0f : 0.0f;
        float o = s;
        if (addin) o += addin[idx];
        out[idx] = o;
        v = (s > 0.0f) ? 0.0f : v;
    }
}

extern "C" void kernel_launch(void* const* d_in, const int* in_sizes, int n_in,
                              void* d_out, int out_size, void* d_ws, size_t ws_size,
                              hipStream_t stream) {
    const float* x    = (const float*)d_in[0];
    const float* w_q  = (const float*)d_in[1];
    const float* bn_q = (const float*)d_in[2];
    const float* w_k  = (const float*)d_in[3];
    const float* bn_k = (const float*)d_in[4];
    const float* w_p  = (const float*)d_in[5];
    const float* b_p  = (const float*)d_in[6];
    const float* bn_p = (const float*)d_in[7];
    const float* w1   = (const float*)d_in[8];
    const float* b1   = (const float*)d_in[9];
    const float* bn1  = (const float*)d_in[10];
    const float* w2   = (const float*)d_in[11];
    const float* b2   = (const float*)d_in[12];
    const float* bn2  = (const float*)d_in[13];

    const size_t SZ1 = (size_t)T_ * B_ * C_ * N_;     // 12,582,912
    const size_t SZA = (size_t)T_ * B_ * 12 * N_;     // 196,608
    const size_t WCC = (size_t)C_ * C_;               // 589,824
    const size_t WCH = (size_t)C_ * CH_;              // 2,359,296

    // --- workspace layout (fixed part 127.4 MB, flex part sized by ws) ---
    char* w = (char*)d_ws;
    float*     qbuf  = (float*)w;     w += SZ1 * 4;      // q_pre -> p_pre -> y
    float*     attnb = (float*)w;     w += SZA * 4;
    _Float16*  R1    = (_Float16*)w;  w += SZ1 * 4;      // XB0/XB1 -> aB -> YB0/YB1
    _Float16*  WQK0  = (_Float16*)w;  w += WCC * 2 * 2;  // [wq; wk] chunk0
    _Float16*  WQK1  = (_Float16*)w;  w += WCC * 2 * 2;
    _Float16*  WP0   = (_Float16*)w;  w += WCC * 2;
    _Float16*  WP1   = (_Float16*)w;  w += WCC * 2;
    _Float16*  W10   = (_Float16*)w;  w += WCH * 2;
    _Float16*  W11   = (_Float16*)w;  w += WCH * 2;
    _Float16*  W20   = (_Float16*)w;  w += WCH * 2;
    _Float16*  W21   = (_Float16*)w;  w += WCH * 2;
    const size_t fixed = (size_t)(w - (char*)d_ws);

    // MLP config ladder (branches only on constant ws_size -> graph-safe):
    //  A : 4 z1-chunks of 768, full s1B, single K=3072 z2 (no RMW)
    //  A2: 8 z1-chunks of 384, full s1B, single z2
    //  B : 4 chunks, accumulating z2 (round-4 proven)
    //  C : 8 chunks, accumulating z2 (round-3 proven)
    const size_t s1full = (size_t)64 * 2 * 96 * 4096 * 2;      // 100,663,296 B
    int nchunk; bool fullS1;
    if      (ws_size >= fixed + (size_t)768 * 64 * 256 * 4 + s1full) { nchunk = 4; fullS1 = true;  }
    else if (ws_size >= fixed + (size_t)384 * 64 * 256 * 4 + s1full) { nchunk = 8; fullS1 = true;  }
    else if (ws_size >= fixed + (size_t)768 * 64 * 256 * 4
                              + (size_t)64 * 2 * 24 * 4096 * 2)      { nchunk = 4; fullS1 = false; }
    else                                                             { nchunk = 8; fullS1 = false; }
    const int chunkM = CH_ / nchunk;        // 768 or 384
    const int mbC = chunkM / 128;           // 6 or 3
    const int KTc = chunkM / 32;            // 24 or 12
    const int KTout = fullS1 ? 96 : KTc;
    float*    z1mc = (float*)w;             // z1 chunk fp32
    _Float16* s1B  = (_Float16*)((char*)z1mc + (size_t)chunkM * 64 * 256 * 4);

    _Float16* XB0 = R1;
    _Float16* XB1 = R1 + SZ1;
    _Float16* aB  = R1;                     // after q/k GEMMs
    _Float16* YB0 = R1;                     // after p GEMM
    _Float16* YB1 = R1 + SZ1;

    float* dob = (float*)d_out;             // k_pre -> (consumed) -> z2 -> out

    const float WS = 4096.f;                // 2^12
    const float XS = 256.f;                 // 2^8
    const float OS_G = 1.f / 1048576.f;     // 2^-20
    const float OS_S = 1.f / 4096.f;        // 2^-12

    const dim3 blk256(256);
    const dim3 blkS(128, 4);

    // --- weight & input splits ---
    splitW3<<<dim3(6, 24, 3), blkS, 0, stream>>>(w_q, w_k, w_p, WQK0, WQK1, WP0, WP1, WS);
    splitW<<<dim3(24, 24), blkS, 0, stream>>>(w1, C_,  W10, W11, 24, WS);
    splitW<<<dim3(6, 96),  blkS, 0, stream>>>(w2, CH_, W20, W21, 96, WS);
    splitB<<<dim3(2, 24, 64), blkS, 0, stream>>>(x, XB0, XB1, 24, XS);

    // --- merged q+k GEMM (general, 3 terms): by 0..5 -> qbuf, 6..11 -> dob ---
    gemm_mfma<2><<<dim3(2, 12, 64), blk256, 0, stream>>>(
        WQK0, WQK1, XB0, XB1, qbuf, dob, 6, C_, nullptr, 0, OS_G, 24, 0, 0, 24, 24);

    // --- fused q->attn; k spikes * attn into blocked fp16 ---
    qattn_kernel<<<dim3(4, 12, B_), dim3(64, 8), 0, stream>>>(qbuf, bn_q, attnb);
    bnlifB<<<dim3(2, 24, B_), blkS, 0, stream>>>(dob, attnb, bn_k, C_, C_, 0, aB, 24, 0);

    // --- p = w_p @ a + b_p (spike, 2 terms); y = x + spike(bn_p(p)) + split ---
    gemm_mfma<1><<<dim3(2, 6, 64), blk256, 0, stream>>>(
        WP0, WP1, aB, nullptr, qbuf, nullptr, 9999, C_, b_p, 0, OS_S, 24, 0, 0, 24, 24);
    bnlif_y_split<<<dim3(2, 24, B_), blkS, 0, stream>>>(qbuf, x, bn_p, YB0, YB1, XS);

    // --- MLP ---
    for (int mc = 0; mc < nchunk; ++mc) {
        gemm_mfma<2><<<dim3(2, mbC, 64), blk256, 0, stream>>>(
            W10, W11, YB0, YB1, z1mc, nullptr, 9999, chunkM,
            b1 + chunkM * mc, 0, OS_G, 24, 0, mbC * mc, 24, 24);
        bnlifB<<<dim3(2, KTc, B_), blkS, 0, stream>>>(
            z1mc, nullptr, bn1, chunkM, CH_, chunkM * mc, s1B, KTout,
            fullS1 ? KTc * mc : 0);
        if (!fullS1) {
            gemm_mfma<1><<<dim3(2, 6, 64), blk256, 0, stream>>>(
                W20, W21, s1B, nullptr, dob, nullptr, 9999, C_,
                (mc == 0) ? b2 : nullptr, mc > 0 ? 1 : 0, OS_S, 96, KTc * mc, 0, KTc, KTc);
        }
    }
    if (fullS1) {
        // single z2 = w2 @ s1 + b2 over full K=3072 (96 k-tiles, no RMW)
        gemm_mfma<1><<<dim3(2, 6, 64), blk256, 0, stream>>>(
            W20, W21, s1B, nullptr, dob, nullptr, 9999, C_, b2, 0, OS_S, 96, 0, 0, 96, 96);
    }

    // --- out = y + spike(bn2(z2)) ---
    bnlif_kernel<<<dim3(C_, B_), blk256, 0, stream>>>(dob, qbuf, dob, bn2, C_, C_);
}

// Round 6
// 863.973 us; speedup vs baseline: 3.4424x; 1.1214x over previous
//
#include <hip/hip_runtime.h>

// T=4, B=16, C=768, H=W=16 -> N=256, Ch=3072, heads=12, d=64
#define T_ 4
#define B_ 16
#define C_ 768
#define N_ 256
#define CH_ 3072

typedef _Float16 f16x8 __attribute__((ext_vector_type(8)));
typedef _Float16 f16x4 __attribute__((ext_vector_type(4)));
typedef float f32x4 __attribute__((ext_vector_type(4)));

// ---------------------------------------------------------------------------
// Blocked operand layout (A=weights, B=activations):
//   per 128(row) x 32(k) tile: 512 chunks of 8 halfs (16B).
//   chunk index c = k8*128 + row; chunk holds k = kt*32 + k8*8 + (0..7).
// A arrays: [mb][KT][512]; B arrays: [bt][nb(2)][KT][512].
// Staging is lane-linear (global_load_lds-compatible) and frag ds_read_b128
// is bank-optimal.
// ---------------------------------------------------------------------------

__device__ __forceinline__ void stage_tile(const _Float16* g, _Float16* l,
                                           int wv, int ln)
{
#pragma unroll
    for (int i = 0; i < 2; ++i) {
        const int c = wv * 128 + i * 64;
        __builtin_amdgcn_global_load_lds(
            (const __attribute__((address_space(1))) void*)(g + (size_t)(c + ln) * 8),
            (__attribute__((address_space(3))) void*)(l + (size_t)c * 8),
            16, 0, 0);
    }
}

// ---------------------------------------------------------------------------
// MFMA GEMM: O[bt, m, n] = oscale * sum_k (A0+A1)[m,k] * (B0[+B1])[k,n] (+bias)
// NB=2: general fp32 operand (A0B0, A0B1, A1B0); NB=1: exact spikes (A0B0, A1B0)
// Tile 128x128, 4 waves of 64x64 (4x4 mfma_f32_16x16x32_f16).
// Dual output: by < splitBy -> Oq, else Ok (m rebased). M = rows per output.
// ---------------------------------------------------------------------------
template <int NB>
__global__ __launch_bounds__(256) void gemm_mfma(
    const _Float16* __restrict__ A0, const _Float16* __restrict__ A1,
    const _Float16* __restrict__ B0, const _Float16* __restrict__ B1,
    float* __restrict__ Oq, float* __restrict__ Ok, int splitBy, int M,
    const float* __restrict__ bias, float oscale,
    int KTA, int ktA0, int mbA0, int KTB, int nkt)
{
    const int nb = blockIdx.x;            // n block (0..1)
    const int by = blockIdx.y;            // output m block
    const int bt = blockIdx.z;            // batch (t*16+b)
    const int mbA = mbA0 + by;

    __shared__ _Float16 lds[(2 + NB) * 4096];

    const int tid = threadIdx.x;
    const int wv = tid >> 6;
    const int ln = tid & 63;
    const int mw = (wv >> 1) * 64;
    const int nw = (wv & 1) * 64;

    f32x4 acc[4][4];
#pragma unroll
    for (int i = 0; i < 4; ++i)
#pragma unroll
        for (int j = 0; j < 4; ++j)
            acc[i][j] = (f32x4){0.f, 0.f, 0.f, 0.f};

    const _Float16* ga0 = A0 + ((size_t)mbA * KTA + ktA0) * 4096;
    const _Float16* ga1 = A1 + ((size_t)mbA * KTA + ktA0) * 4096;
    const _Float16* gb0 = B0 + (((size_t)bt * 2 + nb) * KTB) * 4096;
    const _Float16* gb1 = (NB == 2) ? B1 + (((size_t)bt * 2 + nb) * KTB) * 4096 : nullptr;

    const int ca = (ln >> 4) * 128 + mw + (ln & 15);   // A frag chunk base
    const int cb = (ln >> 4) * 128 + nw + (ln & 15);   // B frag chunk base

    for (int kt = 0; kt < nkt; ++kt) {
        __syncthreads();   // protect previous iteration's LDS frag reads
        stage_tile(ga0, &lds[0], wv, ln);
        stage_tile(ga1, &lds[4096], wv, ln);
        stage_tile(gb0, &lds[2 * 4096], wv, ln);
        if (NB == 2) stage_tile(gb1, &lds[3 * 4096], wv, ln);
        __syncthreads();   // compiler drains vmcnt before barrier

        f16x8 a0[4], a1[4];
#pragma unroll
        for (int mt = 0; mt < 4; ++mt) {
            a0[mt] = *(const f16x8*)&lds[(ca + mt * 16) * 8];
            a1[mt] = *(const f16x8*)&lds[4096 + (ca + mt * 16) * 8];
        }
#pragma unroll
        for (int nt = 0; nt < 4; ++nt) {
            const f16x8 b0 = *(const f16x8*)&lds[2 * 4096 + (cb + nt * 16) * 8];
            f16x8 b1;
            if (NB == 2) b1 = *(const f16x8*)&lds[3 * 4096 + (cb + nt * 16) * 8];
#pragma unroll
            for (int mt = 0; mt < 4; ++mt) {
                acc[mt][nt] = __builtin_amdgcn_mfma_f32_16x16x32_f16(a0[mt], b0, acc[mt][nt], 0, 0, 0);
                acc[mt][nt] = __builtin_amdgcn_mfma_f32_16x16x32_f16(a1[mt], b0, acc[mt][nt], 0, 0, 0);
                if (NB == 2)
                    acc[mt][nt] = __builtin_amdgcn_mfma_f32_16x16x32_f16(a0[mt], b1, acc[mt][nt], 0, 0, 0);
            }
        }
        ga0 += 4096; ga1 += 4096; gb0 += 4096;
        if (NB == 2) gb1 += 4096;
    }

    // Epilogue. C/D layout: col(n) = lane&15, row(m) = (lane>>4)*4 + reg.
    float* Obase = (by < splitBy) ? Oq : Ok;
    const int byl = (by < splitBy) ? by : by - splitBy;
    float* Ob = Obase + (size_t)bt * M * 256;
    const int lm = (ln >> 4) * 4;
    const int lnn = ln & 15;
#pragma unroll
    for (int mt = 0; mt < 4; ++mt) {
#pragma unroll
        for (int r = 0; r < 4; ++r) {
            const int m = byl * 128 + mw + mt * 16 + lm + r;
            const float bb = bias ? bias[m] : 0.0f;
#pragma unroll
            for (int nt = 0; nt < 4; ++nt) {
                const int n = nb * 128 + nw + nt * 16 + lnn;
                Ob[(size_t)m * 256 + n] = acc[mt][nt][r] * oscale + bb;
            }
        }
    }
}

// ---------------------------------------------------------------------------
// Fused MLP layer-1: s1 = LIF(BN1(w1 @ y + b1)), all T steps in one block.
// Grid (2, 24, 16) = (nb, by over Ch/128, b); t-loop inside keeps membrane
// state v in registers; epilogue applies folded BN+LIF and writes spikes
// directly in blocked fp16 B layout (s1B, KT=96). z1 fp32 never materialized.
// 3-term split product (general fp32 B operand y).
// ---------------------------------------------------------------------------
__global__ __launch_bounds__(256) void gemm_mlp1(
    const _Float16* __restrict__ A0, const _Float16* __restrict__ A1,
    const _Float16* __restrict__ B0, const _Float16* __restrict__ B1,
    const float* __restrict__ bias, const float* __restrict__ bnp,
    _Float16* __restrict__ outB, float oscale)
{
    const int nb = blockIdx.x;            // 0..1
    const int by = blockIdx.y;            // 0..23
    const int b  = blockIdx.z;            // 0..15

    __shared__ _Float16 lds[4 * 4096];

    const int tid = threadIdx.x;
    const int wv = tid >> 6;
    const int ln = tid & 63;
    const int mw = (wv >> 1) * 64;
    const int nw = (wv & 1) * 64;
    const int lm = (ln >> 4) * 4;
    const int lnn = ln & 15;

    // folded BN constants for this lane's 16 channels:
    // u = acc*(oscale*sc) + ((bias-mu)*sc + be)
    float Af[16], Bf[16];
#pragma unroll
    for (int mt = 0; mt < 4; ++mt)
#pragma unroll
        for (int r = 0; r < 4; ++r) {
            const int c = by * 128 + mw + mt * 16 + lm + r;
            const float g  = bnp[c];
            const float be = bnp[CH_ + c];
            const float mu = bnp[2 * CH_ + c];
            const float va = bnp[3 * CH_ + c];
            const float sc = g * rsqrtf(va + 1e-5f);
            Af[mt * 4 + r] = oscale * sc;
            Bf[mt * 4 + r] = (bias[c] - mu) * sc + be;
        }

    float v[4][4][4];
#pragma unroll
    for (int i = 0; i < 4; ++i)
#pragma unroll
        for (int j = 0; j < 4; ++j)
#pragma unroll
            for (int r = 0; r < 4; ++r) v[i][j][r] = 0.f;

    const int ca = (ln >> 4) * 128 + mw + lnn;
    const int cb = (ln >> 4) * 128 + nw + lnn;

#pragma unroll 1
    for (int t = 0; t < T_; ++t) {
        const int bt = t * B_ + b;
        const _Float16* ga0 = A0 + ((size_t)by * 24) * 4096;
        const _Float16* ga1 = A1 + ((size_t)by * 24) * 4096;
        const _Float16* gb0 = B0 + (((size_t)bt * 2 + nb) * 24) * 4096;
        const _Float16* gb1 = B1 + (((size_t)bt * 2 + nb) * 24) * 4096;

        f32x4 acc[4][4];
#pragma unroll
        for (int i = 0; i < 4; ++i)
#pragma unroll
            for (int j = 0; j < 4; ++j)
                acc[i][j] = (f32x4){0.f, 0.f, 0.f, 0.f};

        for (int kt = 0; kt < 24; ++kt) {
            __syncthreads();
            stage_tile(ga0, &lds[0], wv, ln);
            stage_tile(ga1, &lds[4096], wv, ln);
            stage_tile(gb0, &lds[2 * 4096], wv, ln);
            stage_tile(gb1, &lds[3 * 4096], wv, ln);
            __syncthreads();

            f16x8 a0[4], a1[4];
#pragma unroll
            for (int mt = 0; mt < 4; ++mt) {
                a0[mt] = *(const f16x8*)&lds[(ca + mt * 16) * 8];
                a1[mt] = *(const f16x8*)&lds[4096 + (ca + mt * 16) * 8];
            }
#pragma unroll
            for (int nt = 0; nt < 4; ++nt) {
                const f16x8 b0 = *(const f16x8*)&lds[2 * 4096 + (cb + nt * 16) * 8];
                const f16x8 b1 = *(const f16x8*)&lds[3 * 4096 + (cb + nt * 16) * 8];
#pragma unroll
                for (int mt = 0; mt < 4; ++mt) {
                    acc[mt][nt] = __builtin_amdgcn_mfma_f32_16x16x32_f16(a0[mt], b0, acc[mt][nt], 0, 0, 0);
                    acc[mt][nt] = __builtin_amdgcn_mfma_f32_16x16x32_f16(a1[mt], b0, acc[mt][nt], 0, 0, 0);
                    acc[mt][nt] = __builtin_amdgcn_mfma_f32_16x16x32_f16(a0[mt], b1, acc[mt][nt], 0, 0, 0);
                }
            }
            ga0 += 4096; ga1 += 4096; gb0 += 4096; gb1 += 4096;
        }

        // BN + LIF epilogue for this t -> blocked fp16 spikes
        _Float16* ob = outB + (((size_t)bt * 2 + nb) * 96) * 4096;
#pragma unroll
        for (int mt = 0; mt < 4; ++mt) {
            const int c0m = by * 128 + mw + mt * 16 + lm;   // lane's first channel
            const int kt_out = c0m >> 5;
            const int k8 = (c0m & 31) >> 3;
            const int j0 = c0m & 7;                         // 0 or 4
#pragma unroll
            for (int nt = 0; nt < 4; ++nt) {
                const int row = nw + nt * 16 + lnn;
                f16x4 hh;
#pragma unroll
                for (int r = 0; r < 4; ++r) {
                    const float u = acc[mt][nt][r] * Af[mt * 4 + r] + Bf[mt * 4 + r];
                    float vv = v[mt][nt][r];
                    vv = vv + (u - vv) * 0.5f;
                    const float sp = (vv >= 1.0f) ? 1.0f : 0.0f;
                    v[mt][nt][r] = (sp > 0.0f) ? 0.0f : vv;
                    hh[r] = (_Float16)sp;
                }
                *(f16x4*)(ob + ((size_t)kt_out * 512 + k8 * 128 + row) * 8 + j0) = hh;
            }
        }
    }
}

// ---------------------------------------------------------------------------
// Weight split: W fp32 [M][ldW] -> 2 fp16 chunk arrays (blocked A layout),
// scaled by 2^12. grid (M/128, KT), block (128,4).
// ---------------------------------------------------------------------------
__global__ void splitW(const float* __restrict__ W, int ldW,
                       _Float16* __restrict__ C0, _Float16* __restrict__ C1,
                       int KT, float scale)
{
    const int mb = blockIdx.x, kt = blockIdx.y;
    const int mm = threadIdx.x, k8 = threadIdx.y;
    const float* src = W + (size_t)(mb * 128 + mm) * ldW + kt * 32 + k8 * 8;
    const size_t cb = (((size_t)mb * KT + kt) * 512 + k8 * 128 + mm) * 8;
    f16x8 h0, h1;
#pragma unroll
    for (int j = 0; j < 8; ++j) {
        const float x = src[j] * scale;
        const _Float16 h = (_Float16)x;
        h0[j] = h;
        h1[j] = (_Float16)(x - (float)h);
    }
    *(f16x8*)(C0 + cb) = h0;
    *(f16x8*)(C1 + cb) = h1;
}

// ---------------------------------------------------------------------------
// Merged split of the three CxC weights: z=0 -> w_q (WQK rows 0..767),
// z=1 -> w_k (WQK rows 768..1535), z=2 -> w_p. grid (6, 24, 3), block (128,4).
// ---------------------------------------------------------------------------
__global__ void splitW3(const float* __restrict__ wq, const float* __restrict__ wk,
                        const float* __restrict__ wp,
                        _Float16* __restrict__ WQK0, _Float16* __restrict__ WQK1,
                        _Float16* __restrict__ WP0,  _Float16* __restrict__ WP1,
                        float scale)
{
    const size_t WCC = (size_t)C_ * C_;
    const int z = blockIdx.z;
    const float* W;
    _Float16 *C0, *C1;
    if (z == 0)      { W = wq; C0 = WQK0;       C1 = WQK1; }
    else if (z == 1) { W = wk; C0 = WQK0 + WCC; C1 = WQK1 + WCC; }
    else             { W = wp; C0 = WP0;        C1 = WP1; }
    const int mb = blockIdx.x, kt = blockIdx.y;
    const int mm = threadIdx.x, k8 = threadIdx.y;
    const float* src = W + (size_t)(mb * 128 + mm) * C_ + kt * 32 + k8 * 8;
    const size_t cb = (((size_t)mb * 24 + kt) * 512 + k8 * 128 + mm) * 8;
    f16x8 h0, h1;
#pragma unroll
    for (int j = 0; j < 8; ++j) {
        const float x = src[j] * scale;
        const _Float16 h = (_Float16)x;
        h0[j] = h;
        h1[j] = (_Float16)(x - (float)h);
    }
    *(f16x8*)(C0 + cb) = h0;
    *(f16x8*)(C1 + cb) = h1;
}

// ---------------------------------------------------------------------------
// Activation split: X fp32 [64][K][256] -> 2 fp16 chunk arrays (blocked B),
// scaled by 2^8. grid (2, KT, 64), block (128,4).
// ---------------------------------------------------------------------------
__global__ void splitB(const float* __restrict__ X,
                       _Float16* __restrict__ C0, _Float16* __restrict__ C1,
                       int KT, float scale)
{
    const int nb = blockIdx.x, kt = blockIdx.y, bt = blockIdx.z;
    const int nn = threadIdx.x, k8 = threadIdx.y;
    const int K = KT * 32;
    const float* src = X + ((size_t)bt * K + kt * 32 + k8 * 8) * 256 + nb * 128 + nn;
    const size_t cb = ((((size_t)bt * 2 + nb) * KT + kt) * 512 + k8 * 128 + nn) * 8;
    f16x8 h0, h1;
#pragma unroll
    for (int j = 0; j < 8; ++j) {
        const float x = src[(size_t)j * 256] * scale;
        const _Float16 h = (_Float16)x;
        h0[j] = h;
        h1[j] = (_Float16)(x - (float)h);
    }
    *(f16x8*)(C0 + cb) = h0;
    *(f16x8*)(C1 + cb) = h1;
}

// ---------------------------------------------------------------------------
// Fused q path: BN+LIF on q_pre, head-sum over d=64, attn LIF -> attn spikes.
// q spikes never materialized. grid (4, 12, 16), block (64, 8).
// ---------------------------------------------------------------------------
__global__ __launch_bounds__(512) void qattn_kernel(
    const float* __restrict__ qpre, const float* __restrict__ bnp,
    float* __restrict__ attn)
{
    const int tx = threadIdx.x, ty = threadIdx.y;
    const int n = blockIdx.x * 64 + tx;
    const int h = blockIdx.y, b = blockIdx.z;
    __shared__ float red[8][64];

    float sc[8], be[8], mu[8];
#pragma unroll
    for (int j = 0; j < 8; ++j) {
        const int c = h * 64 + ty * 8 + j;
        const float g = bnp[c];
        be[j] = bnp[C_ + c];
        mu[j] = bnp[2 * C_ + c];
        sc[j] = g * rsqrtf(bnp[3 * C_ + c] + 1e-5f);
    }
    float v[8];
#pragma unroll
    for (int j = 0; j < 8; ++j) v[j] = 0.f;
    float va = 0.f;

#pragma unroll
    for (int t = 0; t < T_; ++t) {
        const int bt = t * B_ + b;
        const float* p = qpre + ((size_t)bt * C_ + h * 64 + ty * 8) * 256 + n;
        float s = 0.f;
#pragma unroll
        for (int j = 0; j < 8; ++j) {
            const float u = (p[(size_t)j * 256] - mu[j]) * sc[j] + be[j];
            v[j] = v[j] + (u - v[j]) * 0.5f;
            const float sp = (v[j] >= 1.0f) ? 1.0f : 0.0f;
            v[j] = (sp > 0.0f) ? 0.0f : v[j];
            s += sp;
        }
        red[ty][tx] = s;
        __syncthreads();
        if (ty == 0) {
            float tot = red[0][tx];
#pragma unroll
            for (int r = 1; r < 8; ++r) tot += red[r][tx];
            va = va + (tot - va) * 0.5f;
            const float asp = (va >= 1.0f) ? 1.0f : 0.0f;
            va = (asp > 0.0f) ? 0.0f : va;
            attn[((size_t)bt * 12 + h) * 256 + n] = asp;
        }
        __syncthreads();
    }
}

// ---------------------------------------------------------------------------
// BN + LIF over T -> spikes straight into blocked fp16 B layout
// (optional attn multiply for the k path). grid (2, Cc/32, 16), block (128,4).
// ---------------------------------------------------------------------------
__global__ void bnlifB(const float* __restrict__ pre,
                       const float* __restrict__ attn,
                       const float* __restrict__ bnp,
                       int Cc, int Cs, int c0,
                       _Float16* __restrict__ outB, int KTout, int ktOut0)
{
    const int nb = blockIdx.x, kt = blockIdx.y, b = blockIdx.z;
    const int nn = threadIdx.x, k8 = threadIdx.y;
    const int cl = kt * 32 + k8 * 8;
    const int n = nb * 128 + nn;
    float sc[8], be[8], mu[8];
#pragma unroll
    for (int j = 0; j < 8; ++j) {
        const int c = c0 + cl + j;
        const float g = bnp[c];
        be[j] = bnp[Cs + c];
        mu[j] = bnp[2 * Cs + c];
        sc[j] = g * rsqrtf(bnp[3 * Cs + c] + 1e-5f);
    }
    float v[8];
#pragma unroll
    for (int j = 0; j < 8; ++j) v[j] = 0.f;
    const int h = cl >> 6;
#pragma unroll
    for (int t = 0; t < T_; ++t) {
        const int bt = t * B_ + b;
        const float* p = pre + ((size_t)bt * Cc + cl) * 256 + n;
        const float av = attn ? attn[((size_t)bt * 12 + h) * 256 + n] : 1.f;
        f16x8 s;
#pragma unroll
        for (int j = 0; j < 8; ++j) {
            const float u = (p[(size_t)j * 256] - mu[j]) * sc[j] + be[j];
            v[j] = v[j] + (u - v[j]) * 0.5f;
            const float sp = (v[j] >= 1.0f) ? 1.0f : 0.0f;
            v[j] = (sp > 0.0f) ? 0.0f : v[j];
            s[j] = (_Float16)(sp * av);
        }
        *(f16x8*)(outB + ((((size_t)bt * 2 + nb) * KTout + ktOut0 + kt) * 512 + k8 * 128 + nn) * 8) = s;
    }
}

// ---------------------------------------------------------------------------
// Fused y path: y = x + spike(bn_p(p_pre)); writes ONLY the scaled fp16
// 2-chunk blocked split of y (y fp32 is never materialized; the final stage
// reconstructs y = (Y0+Y1)/xscale exactly to ~2^-24 rel).
// grid (2, 24, 16), block (128,4).
// ---------------------------------------------------------------------------
__global__ void bnlif_y_split(const float* __restrict__ ppre,
                              const float* __restrict__ x,
                              const float* __restrict__ bnp,
                              _Float16* __restrict__ Y0, _Float16* __restrict__ Y1,
                              float xscale)
{
    const int nb = blockIdx.x, kt = blockIdx.y, b = blockIdx.z;
    const int nn = threadIdx.x, k8 = threadIdx.y;
    const int cl = kt * 32 + k8 * 8;
    const int n = nb * 128 + nn;
    float sc[8], be[8], mu[8];
#pragma unroll
    for (int j = 0; j < 8; ++j) {
        const int c = cl + j;
        const float g = bnp[c];
        be[j] = bnp[C_ + c];
        mu[j] = bnp[2 * C_ + c];
        sc[j] = g * rsqrtf(bnp[3 * C_ + c] + 1e-5f);
    }
    float v[8];
#pragma unroll
    for (int j = 0; j < 8; ++j) v[j] = 0.f;
#pragma unroll
    for (int t = 0; t < T_; ++t) {
        const int bt = t * B_ + b;
        const size_t off = ((size_t)bt * C_ + cl) * 256 + n;
        const float* p = ppre + off;
        const float* xx = x + off;
        f16x8 h0, h1;
#pragma unroll
        for (int j = 0; j < 8; ++j) {
            const float u = (p[(size_t)j * 256] - mu[j]) * sc[j] + be[j];
            v[j] = v[j] + (u - v[j]) * 0.5f;
            const float sp = (v[j] >= 1.0f) ? 1.0f : 0.0f;
            v[j] = (sp > 0.0f) ? 0.0f : v[j];
            const float ys = (xx[(size_t)j * 256] + sp) * xscale;
            const _Float16 hh = (_Float16)ys;
            h0[j] = hh;
            h1[j] = (_Float16)(ys - (float)hh);
        }
        const size_t cb = ((((size_t)bt * 2 + nb) * 24 + kt) * 512 + k8 * 128 + nn) * 8;
        *(f16x8*)(Y0 + cb) = h0;
        *(f16x8*)(Y1 + cb) = h1;
    }
}

// ---------------------------------------------------------------------------
// Final stage: out = y + spike(bn2(z2)), y reconstructed from the blocked
// fp16 split (y = (Y0+Y1)*yinv). grid (2, 24, 16), block (128,4).
// ---------------------------------------------------------------------------
__global__ void bnlif_out(const float* __restrict__ z2,
                          const _Float16* __restrict__ Y0,
                          const _Float16* __restrict__ Y1,
                          const float* __restrict__ bnp,
                          float* __restrict__ out, float yinv)
{
    const int nb = blockIdx.x, kt = blockIdx.y, b = blockIdx.z;
    const int nn = threadIdx.x, k8 = threadIdx.y;
    const int cl = kt * 32 + k8 * 8;
    const int n = nb * 128 + nn;
    float sc[8], be[8], mu[8];
#pragma unroll
    for (int j = 0; j < 8; ++j) {
        const int c = cl + j;
        const float g = bnp[c];
        be[j] = bnp[C_ + c];
        mu[j] = bnp[2 * C_ + c];
        sc[j] = g * rsqrtf(bnp[3 * C_ + c] + 1e-5f);
    }
    float v[8];
#pragma unroll
    for (int j = 0; j < 8; ++j) v[j] = 0.f;
#pragma unroll
    for (int t = 0; t < T_; ++t) {
        const int bt = t * B_ + b;
        const size_t off = ((size_t)bt * C_ + cl) * 256 + n;
        const float* zp = z2 + off;
        float* op = out + off;
        const size_t ycb = ((((size_t)bt * 2 + nb) * 24 + kt) * 512 + k8 * 128 + nn) * 8;
        const f16x8 y0 = *(const f16x8*)(Y0 + ycb);
        const f16x8 y1 = *(const f16x8*)(Y1 + ycb);
#pragma unroll
        for (int j = 0; j < 8; ++j) {
            const float u = (zp[(size_t)j * 256] - mu[j]) * sc[j] + be[j];
            v[j] = v[j] + (u - v[j]) * 0.5f;
            const float sp = (v[j] >= 1.0f) ? 1.0f : 0.0f;
            v[j] = (sp > 0.0f) ? 0.0f : v[j];
            const float y = ((float)y0[j] + (float)y1[j]) * yinv;
            op[(size_t)j * 256] = y + sp;
        }
    }
}

extern "C" void kernel_launch(void* const* d_in, const int* in_sizes, int n_in,
                              void* d_out, int out_size, void* d_ws, size_t ws_size,
                              hipStream_t stream) {
    const float* x    = (const float*)d_in[0];
    const float* w_q  = (const float*)d_in[1];
    const float* bn_q = (const float*)d_in[2];
    const float* w_k  = (const float*)d_in[3];
    const float* bn_k = (const float*)d_in[4];
    const float* w_p  = (const float*)d_in[5];
    const float* b_p  = (const float*)d_in[6];
    const float* bn_p = (const float*)d_in[7];
    const float* w1   = (const float*)d_in[8];
    const float* b1   = (const float*)d_in[9];
    const float* bn1  = (const float*)d_in[10];
    const float* w2   = (const float*)d_in[11];
    const float* b2   = (const float*)d_in[12];
    const float* bn2  = (const float*)d_in[13];

    const size_t SZ1 = (size_t)T_ * B_ * C_ * N_;     // 12,582,912
    const size_t SZA = (size_t)T_ * B_ * 12 * N_;     // 196,608
    const size_t WCC = (size_t)C_ * C_;               // 589,824
    const size_t WCH = (size_t)C_ * CH_;              // 2,359,296

    // --- workspace layout (~228 MB; round-5 proved ws >= 278 MB) ---
    char* w = (char*)d_ws;
    float*     qbuf  = (float*)w;     w += SZ1 * 4;      // q_pre -> p_pre
    float*     attnb = (float*)w;     w += SZA * 4;
    _Float16*  R1    = (_Float16*)w;  w += SZ1 * 4;      // XB0/XB1 -> aB -> YB0/YB1
    _Float16*  WQK0  = (_Float16*)w;  w += WCC * 2 * 2;  // [wq; wk] chunk0
    _Float16*  WQK1  = (_Float16*)w;  w += WCC * 2 * 2;
    _Float16*  WP0   = (_Float16*)w;  w += WCC * 2;
    _Float16*  WP1   = (_Float16*)w;  w += WCC * 2;
    _Float16*  W10   = (_Float16*)w;  w += WCH * 2;
    _Float16*  W11   = (_Float16*)w;  w += WCH * 2;
    _Float16*  W20   = (_Float16*)w;  w += WCH * 2;
    _Float16*  W21   = (_Float16*)w;  w += WCH * 2;
    _Float16*  s1B   = (_Float16*)w;                     // [64][2][96][4096] halfs

    _Float16* XB0 = R1;
    _Float16* XB1 = R1 + SZ1;
    _Float16* aB  = R1;                     // after q/k GEMMs
    _Float16* YB0 = R1;                     // after p GEMM
    _Float16* YB1 = R1 + SZ1;

    float* dob = (float*)d_out;             // k_pre -> (consumed) -> z2 -> out

    const float WS = 4096.f;                // 2^12
    const float XS = 256.f;                 // 2^8
    const float OS_G = 1.f / 1048576.f;     // 2^-20
    const float OS_S = 1.f / 4096.f;        // 2^-12

    const dim3 blk256(256);
    const dim3 blkS(128, 4);

    // --- weight & input splits ---
    splitW3<<<dim3(6, 24, 3), blkS, 0, stream>>>(w_q, w_k, w_p, WQK0, WQK1, WP0, WP1, WS);
    splitW<<<dim3(24, 24), blkS, 0, stream>>>(w1, C_,  W10, W11, 24, WS);
    splitW<<<dim3(6, 96),  blkS, 0, stream>>>(w2, CH_, W20, W21, 96, WS);
    splitB<<<dim3(2, 24, 64), blkS, 0, stream>>>(x, XB0, XB1, 24, XS);

    // --- merged q+k GEMM (general, 3 terms): by 0..5 -> qbuf, 6..11 -> dob ---
    gemm_mfma<2><<<dim3(2, 12, 64), blk256, 0, stream>>>(
        WQK0, WQK1, XB0, XB1, qbuf, dob, 6, C_, nullptr, OS_G, 24, 0, 0, 24, 24);

    // --- fused q->attn; k spikes * attn into blocked fp16 ---
    qattn_kernel<<<dim3(4, 12, B_), dim3(64, 8), 0, stream>>>(qbuf, bn_q, attnb);
    bnlifB<<<dim3(2, 24, B_), blkS, 0, stream>>>(dob, attnb, bn_k, C_, C_, 0, aB, 24, 0);

    // --- p = w_p @ a + b_p (spike, 2 terms); Y split of y = x + spike(bn_p(p)) ---
    gemm_mfma<1><<<dim3(2, 6, 64), blk256, 0, stream>>>(
        WP0, WP1, aB, nullptr, qbuf, nullptr, 9999, C_, b_p, OS_S, 24, 0, 0, 24, 24);
    bnlif_y_split<<<dim3(2, 24, B_), blkS, 0, stream>>>(qbuf, x, bn_p, YB0, YB1, XS);

    // --- fused MLP layer-1: s1 spikes directly (one launch, all T) ---
    gemm_mlp1<<<dim3(2, 24, B_), blk256, 0, stream>>>(
        W10, W11, YB0, YB1, b1, bn1, s1B, OS_G);

    // --- z2 = w2 @ s1 + b2, single K=3072 pass ---
    gemm_mfma<1><<<dim3(2, 6, 64), blk256, 0, stream>>>(
        W20, W21, s1B, nullptr, dob, nullptr, 9999, C_, b2, OS_S, 96, 0, 0, 96, 96);

    // --- out = y + spike(bn2(z2)), y from Y0+Y1 ---
    bnlif_out<<<dim3(2, 24, B_), blkS, 0, stream>>>(dob, YB0, YB1, bn2, dob, 1.f / XS);
}